// Round 1
// baseline (242.950 us; speedup 1.0000x reference)
//
#include <hip/hip_runtime.h>
#include <hip/hip_bf16.h>
#include <math.h>

// Dims (fixed by the problem)
#define B_  4
#define CIN 256
#define L_  4096      // H*W = 64*64
#define D_  256
#define N_  512
#define K_  4
#define DH  128       // D/2
#define BL  (B_ * L_) // 16384 tokens

#define NCHUNK 32
#define CLEN   (L_ / NCHUNK) // 128

typedef __attribute__((ext_vector_type(8))) short bfrag;
typedef __attribute__((ext_vector_type(4))) float f4;

__device__ __forceinline__ float bf2f(unsigned short u) {
  return __uint_as_float(((unsigned int)u) << 16);
}
__device__ __forceinline__ unsigned short f2bf(float f) {
  unsigned int u = __float_as_uint(f);
  return (unsigned short)((u + 0x7FFFu + ((u >> 16) & 1u)) >> 16);
}

// ---------------------------------------------------------------- utility kernels

__global__ void k_f2bf(const float* __restrict__ in, unsigned short* __restrict__ o, int n) {
  int i = blockIdx.x * blockDim.x + threadIdx.x;
  if (i < n) o[i] = f2bf(in[i]);
}

// feat (B,C,L) f32 -> featT (B*L, C) bf16
__global__ void k_transpose(const float* __restrict__ in, unsigned short* __restrict__ outT) {
  __shared__ float tile[32][33];
  const int b = blockIdx.z;
  const int l0 = blockIdx.x * 32, c0 = blockIdx.y * 32;
  const int tx = threadIdx.x, ty = threadIdx.y;
  const float* p = in + ((size_t)b * CIN + c0 + ty) * L_ + l0 + tx;
#pragma unroll
  for (int i = 0; i < 32; i += 8) tile[ty + i][tx] = p[(size_t)i * L_];
  __syncthreads();
  unsigned short* q = outT + ((size_t)b * L_ + l0 + ty) * CIN + c0 + tx;
#pragma unroll
  for (int i = 0; i < 32; i += 8) q[(size_t)i * CIN] = f2bf(tile[tx][ty + i]);
}

// B_base (K,N,D) -> Bcat (N, K*D) bf16
__global__ void k_bcat(const float* __restrict__ Bb, unsigned short* __restrict__ Bcat) {
  int i = blockIdx.x * 256 + threadIdx.x; // K*N*D = 524288
  int d = i & 255, n = (i >> 8) & 511, k = i >> 17;
  Bcat[((size_t)n << 10) + (k << 8) + d] = f2bf(Bb[i]);
}

// C_base (K,D,N) -> Ccat (D, K*N) bf16
__global__ void k_ccat(const float* __restrict__ Cb, unsigned short* __restrict__ Ccat) {
  int i = blockIdx.x * 256 + threadIdx.x; // K*D*N = 524288
  int n = i & 511, d = (i >> 9) & 255, k = i >> 17;
  Ccat[((size_t)d << 11) + (k << 9) + n] = f2bf(Cb[i]);
}

// alpha from hmid (BL,128 bf16): logits = hmid @ Wa2^T + ba2 ; softmax(K=4)
__global__ void k_alpha(const unsigned short* __restrict__ hmid,
                        const float* __restrict__ Wa2, const float* __restrict__ ba2,
                        float* __restrict__ alpha) {
  __shared__ float w2[K_ * DH];
  for (int i = threadIdx.x; i < K_ * DH; i += 256) w2[i] = Wa2[i];
  __syncthreads();
  const int token = blockIdx.x * 256 + threadIdx.x;
  const uint4* hrow = (const uint4*)(hmid + (size_t)token * DH);
  float a0 = ba2[0], a1 = ba2[1], a2 = ba2[2], a3 = ba2[3];
  for (int c = 0; c < DH / 8; ++c) {
    uint4 v = hrow[c];
    unsigned int uu[4] = {v.x, v.y, v.z, v.w};
#pragma unroll
    for (int q = 0; q < 4; ++q) {
      float h0 = bf2f((unsigned short)(uu[q] & 0xffffu));
      float h1 = bf2f((unsigned short)(uu[q] >> 16));
      int d = c * 8 + q * 2;
      a0 += h0 * w2[0 * DH + d] + h1 * w2[0 * DH + d + 1];
      a1 += h0 * w2[1 * DH + d] + h1 * w2[1 * DH + d + 1];
      a2 += h0 * w2[2 * DH + d] + h1 * w2[2 * DH + d + 1];
      a3 += h0 * w2[3 * DH + d] + h1 * w2[3 * DH + d + 1];
    }
  }
  float m = fmaxf(fmaxf(a0, a1), fmaxf(a2, a3));
  float e0 = expf(a0 - m), e1 = expf(a1 - m), e2 = expf(a2 - m), e3 = expf(a3 - m);
  float inv = 1.f / (e0 + e1 + e2 + e3);
  float* ap = alpha + (size_t)token * 4;
  ap[0] = e0 * inv; ap[1] = e1 * inv; ap[2] = e2 * inv; ap[3] = e3 * inv;
}

// a[bl,n] = sigmoid(sum_k alpha_k * A_base[k,n]) ; block = one token, 512 threads
__global__ void k_a(const float* __restrict__ alpha, const float* __restrict__ Abase,
                    float* __restrict__ a) {
  const int token = blockIdx.x;
  const int n = threadIdx.x;
  const float* ap = alpha + (size_t)token * 4;
  float s = ap[0] * Abase[n] + ap[1] * Abase[N_ + n] + ap[2] * Abase[2 * N_ + n] +
            ap[3] * Abase[3 * N_ + n];
  a[(size_t)token * N_ + n] = 1.f / (1.f + expf(-s));
}

// xk[bl, k*D+d] = alpha_k * x[bl,d]  (bf16)
__global__ void k_xk(const unsigned short* __restrict__ x, const float* __restrict__ alpha,
                     unsigned short* __restrict__ xk) {
  const int token = blockIdx.x;
  const int d = threadIdx.x;
  float xv = bf2f(x[(size_t)token * D_ + d]);
  const float* ap = alpha + (size_t)token * 4;
  unsigned short* o = xk + (size_t)token * (K_ * D_) + d;
  o[0]        = f2bf(ap[0] * xv);
  o[D_]       = f2bf(ap[1] * xv);
  o[2 * D_]   = f2bf(ap[2] * xv);
  o[3 * D_]   = f2bf(ap[3] * xv);
}

// ---------------------------------------------------------------- scan (3-pass)

__global__ void k_scanA(const float* __restrict__ a, const float* __restrict__ u,
                        float* __restrict__ P, float* __restrict__ Hend) {
  const int n = threadIdx.x;           // 512
  const int bc = blockIdx.x;           // B*NCHUNK
  const int b = bc >> 5, c = bc & 31;
  size_t base = ((size_t)b * L_ + (size_t)c * CLEN) * N_ + n;
  float p = 1.f, h = 0.f;
  for (int l = 0; l < CLEN; ++l) {
    float av = a[base], uv = u[base];
    h = av * h + uv;
    p *= av;
    base += N_;
  }
  P[(size_t)bc * N_ + n] = p;
  Hend[(size_t)bc * N_ + n] = h;
}

__global__ void k_scanB(const float* __restrict__ P, const float* __restrict__ Hend,
                        float* __restrict__ Hstart) {
  const int n = threadIdx.x;
  const int b = blockIdx.x;
  float h = 0.f;
  for (int c = 0; c < NCHUNK; ++c) {
    size_t idx = ((size_t)b * NCHUNK + c) * N_ + n;
    Hstart[idx] = h;
    h = P[idx] * h + Hend[idx];
  }
}

// replay with correct h0; fused hk[bl, k*N+n] = alpha_k * h  (bf16)
__global__ void k_scanC(const float* __restrict__ a, const float* __restrict__ u,
                        const float* __restrict__ Hstart, const float* __restrict__ alpha,
                        unsigned short* __restrict__ hk) {
  const int n = threadIdx.x;
  const int bc = blockIdx.x;
  const int b = bc >> 5, c = bc & 31;
  const size_t tok0 = (size_t)b * L_ + (size_t)c * CLEN;
  size_t base = tok0 * N_ + n;
  float h = Hstart[(size_t)bc * N_ + n];
  for (int l = 0; l < CLEN; ++l) {
    float av = a[base], uv = u[base];
    h = av * h + uv;
    const float* ap = alpha + (tok0 + l) * 4;
    unsigned short* o = hk + (tok0 + l) * (K_ * N_) + n;
    o[0]        = f2bf(ap[0] * h);
    o[N_]       = f2bf(ap[1] * h);
    o[2 * N_]   = f2bf(ap[2] * h);
    o[3 * N_]   = f2bf(ap[3] * h);
    base += N_;
  }
}

// ---------------------------------------------------------------- bf16 MFMA GEMM
// C[M,N] = A(M,K) * Bm(N,K)^T  (+bias, +act). A,Bm bf16 K-contiguous row-major.
// m97 structure: 128x128 tile, BK=32, 4 waves (2x2), 4x4 16x16x32 frags/wave,
// global_load_lds width-16 staging into linear LDS.
#define BM 128
#define BN 128
#define BK 32

template <int BIAS /*0 none,1 col,2 row*/, int ACT /*0 none,1 gelu*/, int OUTBF>
__global__ __launch_bounds__(256) void gemm_bt(
    const unsigned short* __restrict__ A, long sA,
    const unsigned short* __restrict__ Bm, long sB,
    const float* __restrict__ bias,
    void* __restrict__ Cv, long sC,
    int M, int N, int Kd) {
  const int zb = blockIdx.z;
  A += (size_t)zb * sA;
  Bm += (size_t)zb * sB;
  const int m0 = blockIdx.x * BM;
  const int n0 = blockIdx.y * BN;
  __shared__ unsigned short As[BM * BK];
  __shared__ unsigned short Bs[BN * BK];
  const int t = threadIdx.x;
  const int lane = t & 63;
  const int w = t >> 6;
  const int wm = (w >> 1) * 64;
  const int wn = (w & 1) * 64;

  f4 acc[4][4];
#pragma unroll
  for (int i = 0; i < 4; ++i)
#pragma unroll
    for (int j = 0; j < 4; ++j) acc[i][j] = (f4){0.f, 0.f, 0.f, 0.f};

  const int rS = t >> 2;        // staging row (0..63)
  const int cS = (t & 3) * 8;   // staging col (bf16 elements)
  const unsigned short* gA = A + (size_t)(m0 + rS) * Kd + cS;
  const unsigned short* gB = Bm + (size_t)(n0 + rS) * Kd + cS;
  unsigned short* lA = As + t * 8;  // linear: wave base + lane*16B
  unsigned short* lB = Bs + t * 8;
  const long rowStep = (long)64 * Kd;

  const int kg = (lane >> 4) * 8;
  const int r16 = lane & 15;

  for (int kt = 0; kt < Kd; kt += BK) {
    __builtin_amdgcn_global_load_lds((const __attribute__((address_space(1))) void*)gA,
                                     (__attribute__((address_space(3))) void*)lA, 16, 0, 0);
    __builtin_amdgcn_global_load_lds((const __attribute__((address_space(1))) void*)(gA + rowStep),
                                     (__attribute__((address_space(3))) void*)(lA + 64 * BK), 16, 0, 0);
    __builtin_amdgcn_global_load_lds((const __attribute__((address_space(1))) void*)gB,
                                     (__attribute__((address_space(3))) void*)lB, 16, 0, 0);
    __builtin_amdgcn_global_load_lds((const __attribute__((address_space(1))) void*)(gB + rowStep),
                                     (__attribute__((address_space(3))) void*)(lB + 64 * BK), 16, 0, 0);
    gA += BK; gB += BK;
    __syncthreads();

    bfrag af[4], bfr[4];
#pragma unroll
    for (int i = 0; i < 4; ++i) {
      af[i]  = *(const bfrag*)(As + (wm + i * 16 + r16) * BK + kg);
      bfr[i] = *(const bfrag*)(Bs + (wn + i * 16 + r16) * BK + kg);
    }
#pragma unroll
    for (int i = 0; i < 4; ++i)
#pragma unroll
      for (int j = 0; j < 4; ++j)
        acc[i][j] = __builtin_amdgcn_mfma_f32_16x16x32_bf16(af[i], bfr[j], acc[i][j], 0, 0, 0);
    __syncthreads();
  }

  // C/D layout: col = lane&15, row = (lane>>4)*4 + reg  [learn_hip m89/m91 verified]
  const int rowBase = m0 + wm + ((lane >> 4) << 2);
  const int colBase = n0 + wn + (lane & 15);
  float* Cf = (float*)Cv + (size_t)zb * sC;
  unsigned short* Cb = (unsigned short*)Cv + (size_t)zb * sC;
#pragma unroll
  for (int i = 0; i < 4; ++i) {
#pragma unroll
    for (int j = 0; j < 4; ++j) {
      const int col = colBase + j * 16;
#pragma unroll
      for (int r = 0; r < 4; ++r) {
        const int row = rowBase + i * 16 + r;
        float v = acc[i][j][r];
        if (BIAS == 1) v += bias[col];
        if (BIAS == 2) v += bias[row];
        if (ACT == 1) v = 0.5f * v * (1.0f + erff(v * 0.70710678118654752f));
        if (OUTBF) Cb[(size_t)row * N + col] = f2bf(v);
        else       Cf[(size_t)row * N + col] = v;
      }
    }
  }
}

// ---------------------------------------------------------------- launch

extern "C" void kernel_launch(void* const* d_in, const int* in_sizes, int n_in,
                              void* d_out, int out_size, void* d_ws, size_t ws_size,
                              hipStream_t stream) {
  const float* feat  = (const float*)d_in[0];
  const float* hf    = (const float*)d_in[1];
  const float* Wf    = (const float*)d_in[2];
  const float* bf    = (const float*)d_in[3];
  const float* Whf   = (const float*)d_in[4];
  const float* bhf   = (const float*)d_in[5];
  const float* Wa1   = (const float*)d_in[6];
  const float* ba1   = (const float*)d_in[7];
  const float* Wa2   = (const float*)d_in[8];
  const float* ba2   = (const float*)d_in[9];
  const float* Abase = (const float*)d_in[10];
  const float* Bbase = (const float*)d_in[11];
  const float* Cbase = (const float*)d_in[12];
  const float* Wout  = (const float*)d_in[13];
  const float* bout  = (const float*)d_in[14];
  float* out = (float*)d_out;

  char* ws = (char*)d_ws;
  size_t off = 0;
  auto alloc = [&](size_t bytes) { void* p = ws + off; off += bytes; return p; };

  // Region A (dead before scanC) — hk aliases it from offset 0.
  unsigned short* featT = (unsigned short*)alloc((size_t)BL * CIN * 2);   // 8.39 MB
  unsigned short* hfT   = (unsigned short*)alloc((size_t)BL * CIN * 2);
  unsigned short* x     = (unsigned short*)alloc((size_t)BL * D_ * 2);
  unsigned short* thf   = (unsigned short*)alloc((size_t)BL * D_ * 2);
  unsigned short* hmid  = (unsigned short*)alloc((size_t)BL * DH * 2);    // 4.19 MB
  unsigned short* xk    = (unsigned short*)alloc((size_t)BL * K_ * D_ * 2); // 33.55 MB
  unsigned short* hk    = (unsigned short*)ws;  // 67.11 MB, aliases region A (71.3 MB)

  // Region B (live across scan)
  float* a_buf  = (float*)alloc((size_t)BL * N_ * 4);    // 33.55 MB
  float* u_buf  = (float*)alloc((size_t)BL * N_ * 4);    // 33.55 MB
  unsigned short* y    = (unsigned short*)alloc((size_t)BL * D_ * 2);
  unsigned short* Bcat = (unsigned short*)alloc((size_t)N_ * K_ * D_ * 2);
  unsigned short* Ccat = (unsigned short*)alloc((size_t)D_ * K_ * N_ * 2);
  float* alpha  = (float*)alloc((size_t)BL * K_ * 4);
  unsigned short* Wfb   = (unsigned short*)alloc((size_t)D_ * CIN * 2);
  unsigned short* Whfb  = (unsigned short*)alloc((size_t)D_ * CIN * 2);
  unsigned short* Wa1b  = (unsigned short*)alloc((size_t)DH * D_ * 2);
  unsigned short* Woutb = (unsigned short*)alloc((size_t)CIN * D_ * 2);
  float* Pc  = (float*)alloc((size_t)B_ * NCHUNK * N_ * 4);
  float* He  = (float*)alloc((size_t)B_ * NCHUNK * N_ * 4);
  float* Hs  = (float*)alloc((size_t)B_ * NCHUNK * N_ * 4);

  if (ws_size < off) return;  // need ~150.4 MB of workspace

  // 1) weight conversions + base-matrix relayouts
  k_f2bf<<<dim3((D_ * CIN + 255) / 256), 256, 0, stream>>>(Wf, Wfb, D_ * CIN);
  k_f2bf<<<dim3((D_ * CIN + 255) / 256), 256, 0, stream>>>(Whf, Whfb, D_ * CIN);
  k_f2bf<<<dim3((DH * D_ + 255) / 256), 256, 0, stream>>>(Wa1, Wa1b, DH * D_);
  k_f2bf<<<dim3((CIN * D_ + 255) / 256), 256, 0, stream>>>(Wout, Woutb, CIN * D_);
  k_bcat<<<dim3(K_ * N_ * D_ / 256), 256, 0, stream>>>(Bbase, Bcat);
  k_ccat<<<dim3(K_ * D_ * N_ / 256), 256, 0, stream>>>(Cbase, Ccat);

  // 2) token-major transposed inputs (bf16)
  k_transpose<<<dim3(L_ / 32, CIN / 32, B_), dim3(32, 8), 0, stream>>>(feat, featT);
  k_transpose<<<dim3(L_ / 32, CIN / 32, B_), dim3(32, 8), 0, stream>>>(hf, hfT);

  // 3) projections: x = featT @ Wf^T + bf ; thf = hfT @ Whf^T + bhf   (bf16 out)
  gemm_bt<1, 0, 1><<<dim3(BL / BM, D_ / BN, 1), 256, 0, stream>>>(
      featT, 0, Wfb, 0, bf, x, 0, BL, D_, CIN);
  gemm_bt<1, 0, 1><<<dim3(BL / BM, D_ / BN, 1), 256, 0, stream>>>(
      hfT, 0, Whfb, 0, bhf, thf, 0, BL, D_, CIN);

  // 4) gating: hmid = gelu(thf @ Wa1^T + ba1) ; alpha = softmax(hmid @ Wa2^T + ba2)
  gemm_bt<1, 1, 1><<<dim3(BL / BM, DH / BN, 1), 256, 0, stream>>>(
      thf, 0, Wa1b, 0, ba1, hmid, 0, BL, DH, D_);
  k_alpha<<<dim3(BL / 256), 256, 0, stream>>>(hmid, Wa2, ba2, alpha);

  // 5) a = sigmoid(alpha @ A_base) ; xk = alpha ⊗ x
  k_a<<<dim3(BL), N_, 0, stream>>>(alpha, Abase, a_buf);
  k_xk<<<dim3(BL), D_, 0, stream>>>(x, alpha, xk);

  // 6) u = xk @ Bcat^T   (f32 out)
  gemm_bt<0, 0, 0><<<dim3(BL / BM, N_ / BN, 1), 256, 0, stream>>>(
      xk, 0, Bcat, 0, nullptr, u_buf, 0, BL, N_, K_ * D_);

  // 7) chunked scan; pass C fuses hk = alpha ⊗ h (bf16)
  k_scanA<<<dim3(B_ * NCHUNK), N_, 0, stream>>>(a_buf, u_buf, Pc, He);
  k_scanB<<<dim3(B_), N_, 0, stream>>>(Pc, He, Hs);
  k_scanC<<<dim3(B_ * NCHUNK), N_, 0, stream>>>(a_buf, u_buf, Hs, alpha, hk);

  // 8) y = hk @ Ccat^T  (bf16 out)
  gemm_bt<0, 0, 1><<<dim3(BL / BM, D_ / BN, 1), 256, 0, stream>>>(
      hk, 0, Ccat, 0, nullptr, y, 0, BL, D_, K_ * N_);

  // 9) out[b,c,l] = Wout @ y_b^T + bout : batched, M=CIN rows, N=L cols
  gemm_bt<2, 0, 0><<<dim3(CIN / BM, L_ / BN, B_), 256, 0, stream>>>(
      Woutb, 0, y, (long)L_ * D_, bout, out, (long)CIN * L_, CIN, L_, D_);
}

// Round 2
// 199.013 us; speedup vs baseline: 1.2208x; 1.2208x over previous
//
#include <hip/hip_runtime.h>
#include <hip/hip_bf16.h>
#include <math.h>

// Dims (fixed by the problem)
#define B_  4
#define CIN 256
#define L_  4096      // H*W = 64*64
#define D_  256
#define N_  512
#define K_  4
#define DH  128       // D/2
#define BL  (B_ * L_) // 16384 tokens

#define NCHUNK 128
#define CLEN   (L_ / NCHUNK) // 32

typedef __attribute__((ext_vector_type(8))) short bfrag;
typedef __attribute__((ext_vector_type(4))) float f4;

__device__ __forceinline__ float bf2f(unsigned short u) {
  return __uint_as_float(((unsigned int)u) << 16);
}
__device__ __forceinline__ unsigned short f2bf(float f) {
  unsigned int u = __float_as_uint(f);
  return (unsigned short)((u + 0x7FFFu + ((u >> 16) & 1u)) >> 16);
}

// ---------------------------------------------------------------- prep (all weight converts, 1 launch)
__global__ void k_prep(const float* __restrict__ Wf, const float* __restrict__ Whf,
                       const float* __restrict__ Wa1, const float* __restrict__ Wout,
                       const float* __restrict__ Bb, const float* __restrict__ Cb,
                       const float* __restrict__ bfv, const float* __restrict__ bhfv,
                       unsigned short* __restrict__ Wfb /*Wfb+Whfb adjacent*/,
                       unsigned short* __restrict__ Wa1b,
                       unsigned short* __restrict__ Woutb,
                       unsigned short* __restrict__ Bb16,
                       unsigned short* __restrict__ Cb16,
                       float* __restrict__ biascat) {
  int i = blockIdx.x * 256 + threadIdx.x;
  if (i < 65536) { Wfb[i] = f2bf(Wf[i]); return; } i -= 65536;
  if (i < 65536) { Wfb[65536 + i] = f2bf(Whf[i]); return; } i -= 65536;
  if (i < 32768) { Wa1b[i] = f2bf(Wa1[i]); return; } i -= 32768;
  if (i < 65536) { Woutb[i] = f2bf(Wout[i]); return; } i -= 65536;
  if (i < 524288) { Bb16[i] = f2bf(Bb[i]); return; } i -= 524288;
  if (i < 524288) { Cb16[i] = f2bf(Cb[i]); return; } i -= 524288;
  if (i < 256) { biascat[i] = bfv[i]; return; } i -= 256;
  if (i < 256) { biascat[256 + i] = bhfv[i]; }
}

// feat/hf (B,C,L) f32 -> (B*L, C) bf16 ; z = which*4 + b
__global__ void k_transpose2(const float* __restrict__ feat, const float* __restrict__ hf,
                             unsigned short* __restrict__ featT /* hfT adjacent */) {
  __shared__ float tile[32][33];
  const int z = blockIdx.z;
  const int b = z & 3, which = z >> 2;
  const float* in = which ? hf : feat;
  unsigned short* outT = featT + (size_t)which * BL * CIN;
  const int l0 = blockIdx.x * 32, c0 = blockIdx.y * 32;
  const int tx = threadIdx.x, ty = threadIdx.y;
  const float* p = in + ((size_t)b * CIN + c0 + ty) * L_ + l0 + tx;
#pragma unroll
  for (int i = 0; i < 32; i += 8) tile[ty + i][tx] = p[(size_t)i * L_];
  __syncthreads();
  unsigned short* q = outT + ((size_t)b * L_ + l0 + ty) * CIN + c0 + tx;
#pragma unroll
  for (int i = 0; i < 32; i += 8) q[(size_t)i * CIN] = f2bf(tile[tx][ty + i]);
}

// alpha: 4 lanes per token. Reduce hmid = gelu(hm0+hm1+ba1), logits = hmid@Wa2^T+ba2, softmax.
__global__ void k_alpha(const float* __restrict__ hm0, const float* __restrict__ hm1,
                        const float* __restrict__ ba1, const float* __restrict__ Wa2,
                        const float* __restrict__ ba2, float* __restrict__ alpha) {
  __shared__ float w2[K_ * DH];
  __shared__ float b1[DH];
  __shared__ float b2[K_];
  for (int i = threadIdx.x; i < K_ * DH; i += 256) w2[i] = Wa2[i];
  if (threadIdx.x < DH) b1[threadIdx.x] = ba1[threadIdx.x];
  if (threadIdx.x < K_) b2[threadIdx.x] = ba2[threadIdx.x];
  __syncthreads();
  const int token = blockIdx.x * 64 + (threadIdx.x >> 2);
  const int q = threadIdx.x & 3;            // 32-d slice owned by this lane
  float a0 = 0.f, a1 = 0.f, a2 = 0.f, a3 = 0.f;
  const size_t base = (size_t)token * DH + q * 32;
#pragma unroll
  for (int j4 = 0; j4 < 8; ++j4) {
    float4 h0 = *(const float4*)(hm0 + base + j4 * 4);
    float4 h1 = *(const float4*)(hm1 + base + j4 * 4);
    const float hv[4] = {h0.x + h1.x, h0.y + h1.y, h0.z + h1.z, h0.w + h1.w};
#pragma unroll
    for (int e = 0; e < 4; ++e) {
      const int d = q * 32 + j4 * 4 + e;
      float g = hv[e] + b1[d];
      g = 0.5f * g * (1.0f + erff(g * 0.70710678118654752f));
      a0 += g * w2[0 * DH + d];
      a1 += g * w2[1 * DH + d];
      a2 += g * w2[2 * DH + d];
      a3 += g * w2[3 * DH + d];
    }
  }
  // butterfly over the 4-lane group
  a0 += __shfl_xor(a0, 1); a1 += __shfl_xor(a1, 1); a2 += __shfl_xor(a2, 1); a3 += __shfl_xor(a3, 1);
  a0 += __shfl_xor(a0, 2); a1 += __shfl_xor(a1, 2); a2 += __shfl_xor(a2, 2); a3 += __shfl_xor(a3, 2);
  a0 += b2[0]; a1 += b2[1]; a2 += b2[2]; a3 += b2[3];
  float m = fmaxf(fmaxf(a0, a1), fmaxf(a2, a3));
  float e0 = expf(a0 - m), e1 = expf(a1 - m), e2 = expf(a2 - m), e3 = expf(a3 - m);
  float inv = 1.f / (e0 + e1 + e2 + e3);
  float my = (q == 0) ? e0 : (q == 1) ? e1 : (q == 2) ? e2 : e3;
  alpha[(size_t)token * 4 + q] = my * inv;
}

// a[bl,n] = sigmoid(sum_k alpha_k * A_base[k,n])
__global__ void k_a(const float* __restrict__ alpha, const float* __restrict__ Abase,
                    float* __restrict__ a) {
  const int token = blockIdx.x;
  const int n = threadIdx.x;
  const float4 ap = *(const float4*)(alpha + (size_t)token * 4);
  float s = ap.x * Abase[n] + ap.y * Abase[N_ + n] + ap.z * Abase[2 * N_ + n] +
            ap.w * Abase[3 * N_ + n];
  a[(size_t)token * N_ + n] = 1.f / (1.f + expf(-s));
}

// ---------------------------------------------------------------- scan (3-pass)
// u_t[n] = sum_k alpha_k * v[t, k*N+n] computed on the fly from bf16 v.

__device__ __forceinline__ float mix_u(const unsigned short* vp, float4 al) {
  return al.x * bf2f(vp[0]) + al.y * bf2f(vp[N_]) + al.z * bf2f(vp[2 * N_]) +
         al.w * bf2f(vp[3 * N_]);
}

__global__ void k_scanA(const float* __restrict__ a, const unsigned short* __restrict__ v,
                        const float* __restrict__ alpha,
                        float* __restrict__ P, float* __restrict__ Hend) {
  const int n = threadIdx.x;           // 512
  const int bc = blockIdx.x;           // B*NCHUNK = 512
  const int b = bc >> 7, c = bc & 127;
  const size_t tok0 = (size_t)b * L_ + (size_t)c * CLEN;
  float p = 1.f, h = 0.f;
  for (int l = 0; l < CLEN; ++l) {
    const size_t t = tok0 + l;
    float4 al = *(const float4*)(alpha + t * 4);
    float uv = mix_u(v + t * (K_ * N_) + n, al);
    float av = a[t * N_ + n];
    h = av * h + uv;
    p *= av;
  }
  P[(size_t)bc * N_ + n] = p;
  Hend[(size_t)bc * N_ + n] = h;
}

__global__ void k_scanB(const float* __restrict__ P, const float* __restrict__ Hend,
                        float* __restrict__ Hstart) {
  const int n = threadIdx.x;
  const int b = blockIdx.x;
  float h = 0.f;
  for (int c = 0; c < NCHUNK; ++c) {
    size_t idx = ((size_t)b * NCHUNK + c) * N_ + n;
    Hstart[idx] = h;
    h = P[idx] * h + Hend[idx];
  }
}

// replay with correct h0, write h as bf16 (alpha folded later in y-combine)
__global__ void k_scanC(const float* __restrict__ a, const unsigned short* __restrict__ v,
                        const float* __restrict__ alpha, const float* __restrict__ Hstart,
                        unsigned short* __restrict__ hbf) {
  const int n = threadIdx.x;
  const int bc = blockIdx.x;
  const int b = bc >> 7, c = bc & 127;
  const size_t tok0 = (size_t)b * L_ + (size_t)c * CLEN;
  float h = Hstart[(size_t)bc * N_ + n];
  for (int l = 0; l < CLEN; ++l) {
    const size_t t = tok0 + l;
    float4 al = *(const float4*)(alpha + t * 4);
    float uv = mix_u(v + t * (K_ * N_) + n, al);
    float av = a[t * N_ + n];
    h = av * h + uv;
    hbf[t * N_ + n] = f2bf(h);
  }
}

// y[bl,d] = sum_k alpha_k * w[bl, k*D+d]  (bf16x8 per thread)
__global__ void k_ycomb(const unsigned short* __restrict__ w, const float* __restrict__ alpha,
                        unsigned short* __restrict__ y) {
  const int g = blockIdx.x * 256 + threadIdx.x;  // BL*32
  const int t = g >> 5, d0 = (g & 31) * 8;
  const float4 ap = *(const float4*)(alpha + (size_t)t * 4);
  const size_t base = (size_t)t * (K_ * D_) + d0;
  uint4 w0 = *(const uint4*)(w + base);
  uint4 w1 = *(const uint4*)(w + base + D_);
  uint4 w2v = *(const uint4*)(w + base + 2 * D_);
  uint4 w3 = *(const uint4*)(w + base + 3 * D_);
  const unsigned int* u0 = (const unsigned int*)&w0;
  const unsigned int* u1 = (const unsigned int*)&w1;
  const unsigned int* u2 = (const unsigned int*)&w2v;
  const unsigned int* u3 = (const unsigned int*)&w3;
  uint4 out;
  unsigned int* po = (unsigned int*)&out;
#pragma unroll
  for (int j = 0; j < 4; ++j) {
    float lo = ap.x * bf2f((unsigned short)(u0[j] & 0xffffu)) +
               ap.y * bf2f((unsigned short)(u1[j] & 0xffffu)) +
               ap.z * bf2f((unsigned short)(u2[j] & 0xffffu)) +
               ap.w * bf2f((unsigned short)(u3[j] & 0xffffu));
    float hi = ap.x * bf2f((unsigned short)(u0[j] >> 16)) +
               ap.y * bf2f((unsigned short)(u1[j] >> 16)) +
               ap.z * bf2f((unsigned short)(u2[j] >> 16)) +
               ap.w * bf2f((unsigned short)(u3[j] >> 16));
    po[j] = (unsigned int)f2bf(lo) | ((unsigned int)f2bf(hi) << 16);
  }
  *(uint4*)(y + (size_t)t * D_ + d0) = out;
}

// ---------------------------------------------------------------- bf16 MFMA GEMM
// C[M,N] = A(M,Kd) * Bm(N,Kd)^T (+bias,+act). Row strides lda/ldb; z advances
// A/Bm/C/bias by sA/sB/sC/bS (elements) — serves batches AND split-K slices.
#define BM 128
#define BN 128
#define BK 32

template <int BIAS /*0 none,1 col,2 row*/, int OUTBF>
__global__ __launch_bounds__(256) void gemm_bt(
    const unsigned short* __restrict__ A, long sA,
    const unsigned short* __restrict__ Bm, long sB,
    const float* __restrict__ bias, long bS,
    void* __restrict__ Cv, long sC,
    int M, int N, int Kd, int lda, int ldb) {
  const int zb = blockIdx.z;
  A += (size_t)zb * sA;
  Bm += (size_t)zb * sB;
  if (BIAS) bias += (size_t)zb * bS;
  const int m0 = blockIdx.x * BM;
  const int n0 = blockIdx.y * BN;
  __shared__ unsigned short As[BM * BK];
  __shared__ unsigned short Bs[BN * BK];
  const int t = threadIdx.x;
  const int lane = t & 63;
  const int w = t >> 6;
  const int wm = (w >> 1) * 64;
  const int wn = (w & 1) * 64;

  f4 acc[4][4];
#pragma unroll
  for (int i = 0; i < 4; ++i)
#pragma unroll
    for (int j = 0; j < 4; ++j) acc[i][j] = (f4){0.f, 0.f, 0.f, 0.f};

  const int rS = t >> 2;
  const int cS = (t & 3) * 8;
  const unsigned short* gA = A + (size_t)(m0 + rS) * lda + cS;
  const unsigned short* gB = Bm + (size_t)(n0 + rS) * ldb + cS;
  unsigned short* lA = As + t * 8;
  unsigned short* lB = Bs + t * 8;
  const long rowStepA = (long)64 * lda;
  const long rowStepB = (long)64 * ldb;

  const int kg = (lane >> 4) * 8;
  const int r16 = lane & 15;

  for (int kt = 0; kt < Kd; kt += BK) {
    __builtin_amdgcn_global_load_lds((const __attribute__((address_space(1))) void*)gA,
                                     (__attribute__((address_space(3))) void*)lA, 16, 0, 0);
    __builtin_amdgcn_global_load_lds((const __attribute__((address_space(1))) void*)(gA + rowStepA),
                                     (__attribute__((address_space(3))) void*)(lA + 64 * BK), 16, 0, 0);
    __builtin_amdgcn_global_load_lds((const __attribute__((address_space(1))) void*)gB,
                                     (__attribute__((address_space(3))) void*)lB, 16, 0, 0);
    __builtin_amdgcn_global_load_lds((const __attribute__((address_space(1))) void*)(gB + rowStepB),
                                     (__attribute__((address_space(3))) void*)(lB + 64 * BK), 16, 0, 0);
    gA += BK; gB += BK;
    __syncthreads();

    bfrag af[4], bfr[4];
#pragma unroll
    for (int i = 0; i < 4; ++i) {
      af[i]  = *(const bfrag*)(As + (wm + i * 16 + r16) * BK + kg);
      bfr[i] = *(const bfrag*)(Bs + (wn + i * 16 + r16) * BK + kg);
    }
#pragma unroll
    for (int i = 0; i < 4; ++i)
#pragma unroll
      for (int j = 0; j < 4; ++j)
        acc[i][j] = __builtin_amdgcn_mfma_f32_16x16x32_bf16(af[i], bfr[j], acc[i][j], 0, 0, 0);
    __syncthreads();
  }

  // C/D layout: col = lane&15, row = (lane>>4)*4 + reg  [learn_hip m89/m91]
  const int rowBase = m0 + wm + ((lane >> 4) << 2);
  const int colBase = n0 + wn + (lane & 15);
  float* Cf = (float*)Cv + (size_t)zb * sC;
  unsigned short* Cb = (unsigned short*)Cv + (size_t)zb * sC;
#pragma unroll
  for (int i = 0; i < 4; ++i) {
#pragma unroll
    for (int j = 0; j < 4; ++j) {
      const int col = colBase + j * 16;
#pragma unroll
      for (int r = 0; r < 4; ++r) {
        const int row = rowBase + i * 16 + r;
        float v = acc[i][j][r];
        if (BIAS == 1) v += bias[col];
        if (BIAS == 2) v += bias[row];
        if (OUTBF) Cb[(size_t)row * N + col] = f2bf(v);
        else       Cf[(size_t)row * N + col] = v;
      }
    }
  }
}

// ---------------------------------------------------------------- launch

extern "C" void kernel_launch(void* const* d_in, const int* in_sizes, int n_in,
                              void* d_out, int out_size, void* d_ws, size_t ws_size,
                              hipStream_t stream) {
  const float* feat  = (const float*)d_in[0];
  const float* hf    = (const float*)d_in[1];
  const float* Wf    = (const float*)d_in[2];
  const float* bfv   = (const float*)d_in[3];
  const float* Whf   = (const float*)d_in[4];
  const float* bhfv  = (const float*)d_in[5];
  const float* Wa1   = (const float*)d_in[6];
  const float* ba1   = (const float*)d_in[7];
  const float* Wa2   = (const float*)d_in[8];
  const float* ba2   = (const float*)d_in[9];
  const float* Abase = (const float*)d_in[10];
  const float* Bbase = (const float*)d_in[11];
  const float* Cbase = (const float*)d_in[12];
  const float* Wout  = (const float*)d_in[13];
  const float* bout  = (const float*)d_in[14];
  float* out = (float*)d_out;

  char* ws = (char*)d_ws;
  size_t off = 0;
  auto alloc = [&](size_t bytes) { void* p = ws + off; off += bytes; return p; };

  unsigned short* Wfb    = (unsigned short*)alloc((size_t)2 * D_ * CIN * 2); // Wfb+Whfb
  unsigned short* Wa1b   = (unsigned short*)alloc((size_t)DH * D_ * 2);
  unsigned short* Woutb  = (unsigned short*)alloc((size_t)CIN * D_ * 2);
  unsigned short* Bb16   = (unsigned short*)alloc((size_t)K_ * N_ * D_ * 2);
  unsigned short* Cb16   = (unsigned short*)alloc((size_t)K_ * D_ * N_ * 2);
  float*          biascat= (float*)alloc((size_t)2 * D_ * 4);
  float*          alpha  = (float*)alloc((size_t)BL * K_ * 4);
  float*          Pc     = (float*)alloc((size_t)B_ * NCHUNK * N_ * 4);
  float*          He     = (float*)alloc((size_t)B_ * NCHUNK * N_ * 4);
  float*          Hs     = (float*)alloc((size_t)B_ * NCHUNK * N_ * 4);
  float*          a_buf  = (float*)alloc((size_t)BL * N_ * 4);
  unsigned short* hbf    = (unsigned short*)alloc((size_t)BL * N_ * 2);
  unsigned short* x      = (unsigned short*)alloc((size_t)BL * D_ * 2);   // x+thf adjacent
  unsigned short* thf    = (unsigned short*)alloc((size_t)BL * D_ * 2);
  unsigned short* featT  = (unsigned short*)alloc((size_t)BL * CIN * 2);  // featT+hfT adjacent
  unsigned short* hfT    = (unsigned short*)alloc((size_t)BL * CIN * 2);
  unsigned short* v      = (unsigned short*)alloc((size_t)BL * K_ * N_ * 2); // 67 MB

  // aliases (regions dead by the time the alias is written)
  float*          hm0 = (float*)featT;  // BL*DH f32 == 8.39 MB, after proj GEMM
  float*          hm1 = (float*)hfT;
  unsigned short* y   = thf;            // BL*D bf16, after hmid GEMM read thf
  unsigned short* wbuf= v;              // BL*K*D bf16 (33.5 MB) fits in v (67 MB), after scanC

  if (ws_size < off) return;  // ~149.7 MB required

  // 1) all weight conversions (one launch)
  k_prep<<<dim3((3 * 65536 + 32768 + 2 * 524288 + 512 + 255) / 256), 256, 0, stream>>>(
      Wf, Whf, Wa1, Wout, Bbase, Cbase, bfv, bhfv, Wfb, Wa1b, Woutb, Bb16, Cb16, biascat);

  // 2) token-major transposed inputs (batched feat+hf)
  k_transpose2<<<dim3(L_ / 32, CIN / 32, 2 * B_), dim3(32, 8), 0, stream>>>(feat, hf, featT);

  // 3) projections batched z=2: x = featT@Wf^T+bf ; thf = hfT@Whf^T+bhf
  gemm_bt<1, 1><<<dim3(BL / BM, D_ / BN, 2), 256, 0, stream>>>(
      featT, (long)BL * CIN, Wfb, (long)D_ * CIN, biascat, D_,
      x, (long)BL * D_, BL, D_, CIN, CIN, CIN);

  // 4) hmid GEMM split-K z=2 (f32 slices, bias+GELU deferred to k_alpha)
  gemm_bt<0, 0><<<dim3(BL / BM, DH / BN, 2), 256, 0, stream>>>(
      thf, 128, Wa1b, 128, nullptr, 0,
      hm0, (long)BL * DH, BL, DH, 128, D_, D_);
  k_alpha<<<dim3(BL / 64), 256, 0, stream>>>(hm0, hm1, ba1, Wa2, ba2, alpha);

  // 5) a = sigmoid(alpha @ A_base)
  k_a<<<dim3(BL), N_, 0, stream>>>(alpha, Abase, a_buf);

  // 6) v[bl, k*N+n] = x @ B_base^T   (N=2048, K=256, grid 2048 blocks)
  gemm_bt<0, 1><<<dim3(BL / BM, (K_ * N_) / BN, 1), 256, 0, stream>>>(
      x, 0, Bb16, 0, nullptr, 0, v, 0, BL, K_ * N_, D_, D_, D_);

  // 7) chunked scan; u folded from v on the fly; pass C writes h (bf16)
  k_scanA<<<dim3(B_ * NCHUNK), N_, 0, stream>>>(a_buf, v, alpha, Pc, He);
  k_scanB<<<dim3(B_), N_, 0, stream>>>(Pc, He, Hs);
  k_scanC<<<dim3(B_ * NCHUNK), N_, 0, stream>>>(a_buf, v, alpha, Hs, hbf);

  // 8) w[bl, k*D+d] = h @ C_base^T   (N=1024, K=512, grid 1024 blocks)
  gemm_bt<0, 1><<<dim3(BL / BM, (K_ * D_) / BN, 1), 256, 0, stream>>>(
      hbf, 0, Cb16, 0, nullptr, 0, wbuf, 0, BL, K_ * D_, N_, N_, N_);

  // 9) y = sum_k alpha_k * w_k  (bf16)
  k_ycomb<<<dim3(BL * 32 / 256), 256, 0, stream>>>(wbuf, alpha, y);

  // 10) out[b,c,l] = Wout @ y_b^T + bout : batched z=4
  gemm_bt<2, 0><<<dim3(CIN / BM, L_ / BN, B_), 256, 0, stream>>>(
      Woutb, 0, y, (long)L_ * D_, bout, 0, out, (long)CIN * L_, CIN, L_, D_, D_, D_);
}

// Round 3
// 189.877 us; speedup vs baseline: 1.2795x; 1.0481x over previous
//
#include <hip/hip_runtime.h>
#include <hip/hip_bf16.h>
#include <math.h>

// Dims (fixed by the problem)
#define B_  4
#define CIN 256
#define L_  4096      // H*W = 64*64
#define D_  256
#define N_  512
#define K_  4
#define DH  128       // D/2
#define BL  (B_ * L_) // 16384 tokens

#define NCHUNK 128
#define CLEN   (L_ / NCHUNK) // 32

typedef __attribute__((ext_vector_type(8))) short bfrag;
typedef __attribute__((ext_vector_type(4))) float f4;

__device__ __forceinline__ float bf2f(unsigned short u) {
  return __uint_as_float(((unsigned int)u) << 16);
}
__device__ __forceinline__ unsigned short f2bf(float f) {
  unsigned int u = __float_as_uint(f);
  return (unsigned short)((u + 0x7FFFu + ((u >> 16) & 1u)) >> 16);
}

// ---------------------------------------------------------------- prep (all weight converts, 1 launch)
// Bb16 row (n*4+k) = B_base[k,n,:]   (K-contig over d)
// Cb16 row (d*4+k) = C_base[k,d,:]   (K-contig over n)
__global__ void k_prep(const float* __restrict__ Wf, const float* __restrict__ Whf,
                       const float* __restrict__ Wa1, const float* __restrict__ Wout,
                       const float* __restrict__ Bb, const float* __restrict__ Cb,
                       const float* __restrict__ bfv, const float* __restrict__ bhfv,
                       unsigned short* __restrict__ Wfb /*Wfb+Whfb adjacent*/,
                       unsigned short* __restrict__ Wa1b,
                       unsigned short* __restrict__ Woutb,
                       unsigned short* __restrict__ Bb16,
                       unsigned short* __restrict__ Cb16,
                       float* __restrict__ biascat) {
  int i = blockIdx.x * 256 + threadIdx.x;
  if (i < 65536) { Wfb[i] = f2bf(Wf[i]); return; } i -= 65536;
  if (i < 65536) { Wfb[65536 + i] = f2bf(Whf[i]); return; } i -= 65536;
  if (i < 32768) { Wa1b[i] = f2bf(Wa1[i]); return; } i -= 32768;
  if (i < 65536) { Woutb[i] = f2bf(Wout[i]); return; } i -= 65536;
  if (i < 524288) {  // B_base (K,N,D): i = (k<<17)|(n<<8)|d
    int d = i & 255, n = (i >> 8) & 511, k = i >> 17;
    Bb16[(((size_t)n << 2) | k) << 8 | d] = f2bf(Bb[i]);
    return;
  } i -= 524288;
  if (i < 524288) {  // C_base (K,D,N): i = (k<<17)|(d<<9)|nn
    int nn = i & 511, d = (i >> 9) & 255, k = i >> 17;
    Cb16[(((size_t)d << 2) | k) << 9 | nn] = f2bf(Cb[i]);
    return;
  } i -= 524288;
  if (i < 256) { biascat[i] = bfv[i]; return; } i -= 256;
  if (i < 256) { biascat[256 + i] = bhfv[i]; }
}

// feat/hf (B,C,L) f32 -> (B*L, C) bf16 ; z = which*4 + b
__global__ void k_transpose2(const float* __restrict__ feat, const float* __restrict__ hf,
                             unsigned short* __restrict__ featT /* hfT adjacent */) {
  __shared__ float tile[32][33];
  const int z = blockIdx.z;
  const int b = z & 3, which = z >> 2;
  const float* in = which ? hf : feat;
  unsigned short* outT = featT + (size_t)which * BL * CIN;
  const int l0 = blockIdx.x * 32, c0 = blockIdx.y * 32;
  const int tx = threadIdx.x, ty = threadIdx.y;
  const float* p = in + ((size_t)b * CIN + c0 + ty) * L_ + l0 + tx;
#pragma unroll
  for (int i = 0; i < 32; i += 8) tile[ty + i][tx] = p[(size_t)i * L_];
  __syncthreads();
  unsigned short* q = outT + ((size_t)b * L_ + l0 + ty) * CIN + c0 + tx;
#pragma unroll
  for (int i = 0; i < 32; i += 8) q[(size_t)i * CIN] = f2bf(tile[tx][ty + i]);
}

// alpha: 4 lanes per token. hmid = gelu(hm0+hm1+ba1), logits = hmid@Wa2^T+ba2, softmax.
__global__ void k_alpha(const float* __restrict__ hm0, const float* __restrict__ hm1,
                        const float* __restrict__ ba1, const float* __restrict__ Wa2,
                        const float* __restrict__ ba2, float* __restrict__ alpha) {
  __shared__ float w2[K_ * DH];
  __shared__ float b1[DH];
  __shared__ float b2[K_];
  for (int i = threadIdx.x; i < K_ * DH; i += 256) w2[i] = Wa2[i];
  if (threadIdx.x < DH) b1[threadIdx.x] = ba1[threadIdx.x];
  if (threadIdx.x < K_) b2[threadIdx.x] = ba2[threadIdx.x];
  __syncthreads();
  const int token = blockIdx.x * 64 + (threadIdx.x >> 2);
  const int q = threadIdx.x & 3;            // 32-d slice owned by this lane
  float a0 = 0.f, a1 = 0.f, a2 = 0.f, a3 = 0.f;
  const size_t base = (size_t)token * DH + q * 32;
#pragma unroll
  for (int j4 = 0; j4 < 8; ++j4) {
    float4 h0 = *(const float4*)(hm0 + base + j4 * 4);
    float4 h1 = *(const float4*)(hm1 + base + j4 * 4);
    const float hv[4] = {h0.x + h1.x, h0.y + h1.y, h0.z + h1.z, h0.w + h1.w};
#pragma unroll
    for (int e = 0; e < 4; ++e) {
      const int d = q * 32 + j4 * 4 + e;
      float g = hv[e] + b1[d];
      g = 0.5f * g * (1.0f + erff(g * 0.70710678118654752f));
      a0 += g * w2[0 * DH + d];
      a1 += g * w2[1 * DH + d];
      a2 += g * w2[2 * DH + d];
      a3 += g * w2[3 * DH + d];
    }
  }
  a0 += __shfl_xor(a0, 1); a1 += __shfl_xor(a1, 1); a2 += __shfl_xor(a2, 1); a3 += __shfl_xor(a3, 1);
  a0 += __shfl_xor(a0, 2); a1 += __shfl_xor(a1, 2); a2 += __shfl_xor(a2, 2); a3 += __shfl_xor(a3, 2);
  a0 += b2[0]; a1 += b2[1]; a2 += b2[2]; a3 += b2[3];
  float m = fmaxf(fmaxf(a0, a1), fmaxf(a2, a3));
  float e0 = expf(a0 - m), e1 = expf(a1 - m), e2 = expf(a2 - m), e3 = expf(a3 - m);
  float inv = 1.f / (e0 + e1 + e2 + e3);
  float my = (q == 0) ? e0 : (q == 1) ? e1 : (q == 2) ? e2 : e3;
  alpha[(size_t)token * 4 + q] = my * inv;
}

// ---------------------------------------------------------------- scan (3-pass)
// a recomputed from alpha & A_base in-register; u read directly (f32).

__global__ void k_scanA(const float* __restrict__ u, const float* __restrict__ alpha,
                        const float* __restrict__ Abase,
                        float* __restrict__ P, float* __restrict__ Hend) {
  const int n = threadIdx.x;           // 512
  const int bc = blockIdx.x;           // B*NCHUNK = 512
  const int b = bc >> 7, c = bc & 127;
  const float A0 = Abase[n], A1 = Abase[N_ + n], A2 = Abase[2 * N_ + n], A3 = Abase[3 * N_ + n];
  const size_t tok0 = (size_t)b * L_ + (size_t)c * CLEN;
  float p = 1.f, h = 0.f;
  for (int l = 0; l < CLEN; ++l) {
    const size_t t = tok0 + l;
    float4 al = *(const float4*)(alpha + t * 4);
    float s = al.x * A0 + al.y * A1 + al.z * A2 + al.w * A3;
    float av = 1.f / (1.f + expf(-s));
    float uv = u[t * N_ + n];
    h = av * h + uv;
    p *= av;
  }
  P[(size_t)bc * N_ + n] = p;
  Hend[(size_t)bc * N_ + n] = h;
}

__global__ void k_scanB(const float* __restrict__ P, const float* __restrict__ Hend,
                        float* __restrict__ Hstart) {
  const int n = threadIdx.x;
  const int b = blockIdx.x;
  float h = 0.f;
  for (int c = 0; c < NCHUNK; ++c) {
    size_t idx = ((size_t)b * NCHUNK + c) * N_ + n;
    Hstart[idx] = h;
    h = P[idx] * h + Hend[idx];
  }
}

__global__ void k_scanC(const float* __restrict__ u, const float* __restrict__ alpha,
                        const float* __restrict__ Abase, const float* __restrict__ Hstart,
                        unsigned short* __restrict__ hbf) {
  const int n = threadIdx.x;
  const int bc = blockIdx.x;
  const int b = bc >> 7, c = bc & 127;
  const float A0 = Abase[n], A1 = Abase[N_ + n], A2 = Abase[2 * N_ + n], A3 = Abase[3 * N_ + n];
  const size_t tok0 = (size_t)b * L_ + (size_t)c * CLEN;
  float h = Hstart[(size_t)bc * N_ + n];
  for (int l = 0; l < CLEN; ++l) {
    const size_t t = tok0 + l;
    float4 al = *(const float4*)(alpha + t * 4);
    float s = al.x * A0 + al.y * A1 + al.z * A2 + al.w * A3;
    float av = 1.f / (1.f + expf(-s));
    float uv = u[t * N_ + n];
    h = av * h + uv;
    hbf[t * N_ + n] = f2bf(h);
  }
}

// ---------------------------------------------------------------- bf16 MFMA GEMM
// C[M,N] = A(M,Kd) * Bm(N,Kd)^T. 2-phase double-buffered LDS (T3 minimum recipe):
// stage tile kt+1 before compute of tile kt; single __syncthreads per iter.
// EPI: 0 = f32 out (+bias), 1 = bf16 out (+bias),
//      2 = alpha-mix over 4-lane k-groups -> f32 out (ld = N/4)
//      3 = alpha-mix -> bf16 out (ld = N/4)
#define BM 128
#define BN 128
#define BK 32

template <int BIAS /*0,1 col,2 row*/, int EPI>
__global__ __launch_bounds__(256) void gemm_bt(
    const unsigned short* __restrict__ A, long sA,
    const unsigned short* __restrict__ Bm, long sB,
    const float* __restrict__ bias, long bS,
    const float* __restrict__ alphaP,
    void* __restrict__ Cv, long sC,
    int M, int N, int Kd, int lda, int ldb) {
  const int zb = blockIdx.z;
  A += (size_t)zb * sA;
  Bm += (size_t)zb * sB;
  if (BIAS) bias += (size_t)zb * bS;
  const int m0 = blockIdx.x * BM;
  const int n0 = blockIdx.y * BN;
  __shared__ unsigned short As[2 * BM * BK];
  __shared__ unsigned short Bs[2 * BN * BK];
  const int t = threadIdx.x;
  const int lane = t & 63;
  const int w = t >> 6;
  const int wm = (w >> 1) * 64;
  const int wn = (w & 1) * 64;

  f4 acc[4][4];
#pragma unroll
  for (int i = 0; i < 4; ++i)
#pragma unroll
    for (int j = 0; j < 4; ++j) acc[i][j] = (f4){0.f, 0.f, 0.f, 0.f};

  const int rS = t >> 2;
  const int cS = (t & 3) * 8;
  const unsigned short* gA = A + (size_t)(m0 + rS) * lda + cS;
  const unsigned short* gB = Bm + (size_t)(n0 + rS) * ldb + cS;
  const long rowStepA = (long)64 * lda;
  const long rowStepB = (long)64 * ldb;

  const int kg = (lane >> 4) * 8;
  const int r16 = lane & 15;

#define STAGE(buf, kt)                                                                       \
  do {                                                                                       \
    const unsigned short* sA_ = gA + (size_t)(kt) * BK;                                      \
    const unsigned short* sB_ = gB + (size_t)(kt) * BK;                                      \
    unsigned short* dA_ = As + (buf) * (BM * BK) + t * 8;                                    \
    unsigned short* dB_ = Bs + (buf) * (BN * BK) + t * 8;                                    \
    __builtin_amdgcn_global_load_lds((const __attribute__((address_space(1))) void*)sA_,     \
                                     (__attribute__((address_space(3))) void*)dA_, 16, 0, 0);\
    __builtin_amdgcn_global_load_lds(                                                        \
        (const __attribute__((address_space(1))) void*)(sA_ + rowStepA),                     \
        (__attribute__((address_space(3))) void*)(dA_ + 64 * BK), 16, 0, 0);                 \
    __builtin_amdgcn_global_load_lds((const __attribute__((address_space(1))) void*)sB_,     \
                                     (__attribute__((address_space(3))) void*)dB_, 16, 0, 0);\
    __builtin_amdgcn_global_load_lds(                                                        \
        (const __attribute__((address_space(1))) void*)(sB_ + rowStepB),                     \
        (__attribute__((address_space(3))) void*)(dB_ + 64 * BK), 16, 0, 0);                 \
  } while (0)

  const int nIter = Kd / BK;
  STAGE(0, 0);
  __syncthreads();
  int cur = 0;
  for (int kt = 0; kt < nIter; ++kt) {
    if (kt + 1 < nIter) STAGE(cur ^ 1, kt + 1);
    const unsigned short* Ab = As + cur * (BM * BK);
    const unsigned short* Bb2 = Bs + cur * (BN * BK);
    bfrag af[4], bfr[4];
#pragma unroll
    for (int i = 0; i < 4; ++i) {
      af[i]  = *(const bfrag*)(Ab + (wm + i * 16 + r16) * BK + kg);
      bfr[i] = *(const bfrag*)(Bb2 + (wn + i * 16 + r16) * BK + kg);
    }
#pragma unroll
    for (int i = 0; i < 4; ++i)
#pragma unroll
      for (int j = 0; j < 4; ++j)
        acc[i][j] = __builtin_amdgcn_mfma_f32_16x16x32_bf16(af[i], bfr[j], acc[i][j], 0, 0, 0);
    __syncthreads();
    cur ^= 1;
  }
#undef STAGE

  // C/D layout: col = lane&15, row = (lane>>4)*4 + reg  [learn_hip m89/m91]
  const int rowBase = m0 + wm + ((lane >> 4) << 2);
  const int colBase = n0 + wn + (lane & 15);

  if (EPI >= 2) {
    // cols are (n*4 + k); 4-lane shuffle-reduce with per-token alpha weights.
    const int kq = lane & 3;
    const int NO = N >> 2;
    float av[4][4];
#pragma unroll
    for (int i = 0; i < 4; ++i)
#pragma unroll
      for (int r = 0; r < 4; ++r)
        av[i][r] = alphaP[(size_t)(rowBase + i * 16 + r) * 4 + kq];
    float* Cf = (float*)Cv + (size_t)zb * sC;
    unsigned short* Cb = (unsigned short*)Cv + (size_t)zb * sC;
#pragma unroll
    for (int i = 0; i < 4; ++i)
#pragma unroll
      for (int j = 0; j < 4; ++j) {
        const int col = colBase + j * 16;
#pragma unroll
        for (int r = 0; r < 4; ++r) {
          float p = av[i][r] * acc[i][j][r];
          p += __shfl_xor(p, 1);
          p += __shfl_xor(p, 2);
          if (kq == 0) {
            const int row = rowBase + i * 16 + r;
            if (EPI == 2) Cf[(size_t)row * NO + (col >> 2)] = p;
            else          Cb[(size_t)row * NO + (col >> 2)] = f2bf(p);
          }
        }
      }
    return;
  }

  float* Cf = (float*)Cv + (size_t)zb * sC;
  unsigned short* Cb = (unsigned short*)Cv + (size_t)zb * sC;
#pragma unroll
  for (int i = 0; i < 4; ++i) {
#pragma unroll
    for (int j = 0; j < 4; ++j) {
      const int col = colBase + j * 16;
#pragma unroll
      for (int r = 0; r < 4; ++r) {
        const int row = rowBase + i * 16 + r;
        float v = acc[i][j][r];
        if (BIAS == 1) v += bias[col];
        if (BIAS == 2) v += bias[row];
        if (EPI == 1) Cb[(size_t)row * N + col] = f2bf(v);
        else          Cf[(size_t)row * N + col] = v;
      }
    }
  }
}

// ---------------------------------------------------------------- launch

extern "C" void kernel_launch(void* const* d_in, const int* in_sizes, int n_in,
                              void* d_out, int out_size, void* d_ws, size_t ws_size,
                              hipStream_t stream) {
  const float* feat  = (const float*)d_in[0];
  const float* hf    = (const float*)d_in[1];
  const float* Wf    = (const float*)d_in[2];
  const float* bfv   = (const float*)d_in[3];
  const float* Whf   = (const float*)d_in[4];
  const float* bhfv  = (const float*)d_in[5];
  const float* Wa1   = (const float*)d_in[6];
  const float* ba1   = (const float*)d_in[7];
  const float* Wa2   = (const float*)d_in[8];
  const float* ba2   = (const float*)d_in[9];
  const float* Abase = (const float*)d_in[10];
  const float* Bbase = (const float*)d_in[11];
  const float* Cbase = (const float*)d_in[12];
  const float* Wout  = (const float*)d_in[13];
  const float* bout  = (const float*)d_in[14];
  float* out = (float*)d_out;

  char* ws = (char*)d_ws;
  size_t off = 0;
  auto alloc = [&](size_t bytes) { void* p = ws + off; off += bytes; return p; };

  unsigned short* Wfb    = (unsigned short*)alloc((size_t)2 * D_ * CIN * 2); // Wfb+Whfb
  unsigned short* Wa1b   = (unsigned short*)alloc((size_t)DH * D_ * 2);
  unsigned short* Woutb  = (unsigned short*)alloc((size_t)CIN * D_ * 2);
  unsigned short* Bb16   = (unsigned short*)alloc((size_t)K_ * N_ * D_ * 2);
  unsigned short* Cb16   = (unsigned short*)alloc((size_t)K_ * D_ * N_ * 2);
  float*          biascat= (float*)alloc((size_t)2 * D_ * 4);
  float*          alpha  = (float*)alloc((size_t)BL * K_ * 4);
  float*          Pc     = (float*)alloc((size_t)B_ * NCHUNK * N_ * 4);
  float*          He     = (float*)alloc((size_t)B_ * NCHUNK * N_ * 4);
  float*          Hs     = (float*)alloc((size_t)B_ * NCHUNK * N_ * 4);
  unsigned short* hbf    = (unsigned short*)alloc((size_t)BL * N_ * 2);
  unsigned short* x      = (unsigned short*)alloc((size_t)BL * D_ * 2);
  unsigned short* thf    = (unsigned short*)alloc((size_t)BL * D_ * 2);
  unsigned short* featT  = (unsigned short*)alloc((size_t)BL * CIN * 2);
  unsigned short* hfT    = (unsigned short*)alloc((size_t)BL * CIN * 2);
  float*          u      = (float*)alloc((size_t)BL * N_ * 4);   // 33.5 MB

  // aliases (dead regions)
  float*          hm0 = (float*)featT;  // BL*DH f32 = 8.39 MB, after proj GEMM
  float*          hm1 = (float*)hfT;
  unsigned short* y   = thf;            // BL*D bf16, after hmid GEMM read thf

  if (ws_size < off) return;  // ~91 MB required

  // 1) weight conversions + base relayouts
  k_prep<<<dim3((3 * 65536 + 32768 + 2 * 524288 + 512 + 255) / 256), 256, 0, stream>>>(
      Wf, Whf, Wa1, Wout, Bbase, Cbase, bfv, bhfv, Wfb, Wa1b, Woutb, Bb16, Cb16, biascat);

  // 2) token-major transposed inputs (batched feat+hf)
  k_transpose2<<<dim3(L_ / 32, CIN / 32, 2 * B_), dim3(32, 8), 0, stream>>>(feat, hf, featT);

  // 3) projections batched z=2: x = featT@Wf^T+bf ; thf = hfT@Whf^T+bhf
  gemm_bt<1, 1><<<dim3(BL / BM, D_ / BN, 2), 256, 0, stream>>>(
      featT, (long)BL * CIN, Wfb, (long)D_ * CIN, biascat, D_, nullptr,
      x, (long)BL * D_, BL, D_, CIN, CIN, CIN);

  // 4) hmid GEMM split-K z=2 (f32 slices; bias+GELU deferred to k_alpha)
  gemm_bt<0, 0><<<dim3(BL / BM, DH / BN, 2), 256, 0, stream>>>(
      thf, 128, Wa1b, 128, nullptr, 0, nullptr,
      hm0, (long)BL * DH, BL, DH, 128, D_, D_);
  k_alpha<<<dim3(BL / 64), 256, 0, stream>>>(hm0, hm1, ba1, Wa2, ba2, alpha);

  // 5) u[t,n] = sum_k alpha_k (x @ B_base^T) : mix fused in epilogue (EPI=2)
  gemm_bt<0, 2><<<dim3(BL / BM, (K_ * N_) / BN, 1), 256, 0, stream>>>(
      x, 0, Bb16, 0, nullptr, 0, alpha, u, 0, BL, K_ * N_, D_, D_, D_);

  // 6) chunked scan; a recomputed in-register; pass C writes h (bf16)
  k_scanA<<<dim3(B_ * NCHUNK), N_, 0, stream>>>(u, alpha, Abase, Pc, He);
  k_scanB<<<dim3(B_), N_, 0, stream>>>(Pc, He, Hs);
  k_scanC<<<dim3(B_ * NCHUNK), N_, 0, stream>>>(u, alpha, Abase, Hs, hbf);

  // 7) y[t,d] = sum_k alpha_k (h @ C_base^T) : mix fused in epilogue (EPI=3)
  gemm_bt<0, 3><<<dim3(BL / BM, (K_ * D_) / BN, 1), 256, 0, stream>>>(
      hbf, 0, Cb16, 0, nullptr, 0, alpha, y, 0, BL, K_ * D_, N_, N_, N_);

  // 8) out[b,c,l] = Wout @ y_b^T + bout : batched z=4
  gemm_bt<2, 0><<<dim3(CIN / BM, L_ / BN, B_), 256, 0, stream>>>(
      Woutb, 0, y, (long)L_ * D_, bout, 0, nullptr, out, (long)CIN * L_, CIN, L_, D_, D_, D_);
}

// Round 4
// 163.894 us; speedup vs baseline: 1.4824x; 1.1585x over previous
//
#include <hip/hip_runtime.h>
#include <hip/hip_bf16.h>
#include <math.h>

// Dims (fixed by the problem)
#define B_  4
#define CIN 256
#define L_  4096      // H*W = 64*64
#define D_  256
#define N_  512
#define K_  4
#define DH  128       // D/2
#define BL  (B_ * L_) // 16384 tokens

#define NCHUNK 128
#define CLEN   (L_ / NCHUNK) // 32

typedef __attribute__((ext_vector_type(8))) short bfrag;
typedef __attribute__((ext_vector_type(4))) float f4;

__device__ __forceinline__ float bf2f(unsigned short u) {
  return __uint_as_float(((unsigned int)u) << 16);
}
__device__ __forceinline__ unsigned short f2bf(float f) {
  unsigned int u = __float_as_uint(f);
  return (unsigned short)((u + 0x7FFFu + ((u >> 16) & 1u)) >> 16);
}

// ---------------------------------------------------------------- prep (all weight converts, 1 launch)
// Bb16 row (n*4+k) = B_base[k,n,:]   (K-contig over d)
// Cb16 row (d*4+k) = C_base[k,d,:]   (K-contig over n)
__global__ void k_prep(const float* __restrict__ Wf, const float* __restrict__ Whf,
                       const float* __restrict__ Wa1, const float* __restrict__ Wout,
                       const float* __restrict__ Bb, const float* __restrict__ Cb,
                       const float* __restrict__ bfv, const float* __restrict__ bhfv,
                       unsigned short* __restrict__ Wfb /*Wfb+Whfb adjacent*/,
                       unsigned short* __restrict__ Wa1b,
                       unsigned short* __restrict__ Woutb,
                       unsigned short* __restrict__ Bb16,
                       unsigned short* __restrict__ Cb16,
                       float* __restrict__ biascat) {
  int i = blockIdx.x * 256 + threadIdx.x;
  if (i < 65536) { Wfb[i] = f2bf(Wf[i]); return; } i -= 65536;
  if (i < 65536) { Wfb[65536 + i] = f2bf(Whf[i]); return; } i -= 65536;
  if (i < 32768) { Wa1b[i] = f2bf(Wa1[i]); return; } i -= 32768;
  if (i < 65536) { Woutb[i] = f2bf(Wout[i]); return; } i -= 65536;
  if (i < 524288) {  // B_base (K,N,D): i = (k<<17)|(n<<8)|d
    int d = i & 255, n = (i >> 8) & 511, k = i >> 17;
    Bb16[(((size_t)n << 2) | k) << 8 | d] = f2bf(Bb[i]);
    return;
  } i -= 524288;
  if (i < 524288) {  // C_base (K,D,N): i = (k<<17)|(d<<9)|nn
    int nn = i & 511, d = (i >> 9) & 255, k = i >> 17;
    Cb16[(((size_t)d << 2) | k) << 9 | nn] = f2bf(Cb[i]);
    return;
  } i -= 524288;
  if (i < 256) { biascat[i] = bfv[i]; return; } i -= 256;
  if (i < 256) { biascat[256 + i] = bhfv[i]; }
}

// feat/hf (B,C,L) f32 -> (B*L, C) bf16 ; z = which*4 + b
__global__ void k_transpose2(const float* __restrict__ feat, const float* __restrict__ hf,
                             unsigned short* __restrict__ featT /* hfT adjacent */) {
  __shared__ float tile[32][33];
  const int z = blockIdx.z;
  const int b = z & 3, which = z >> 2;
  const float* in = which ? hf : feat;
  unsigned short* outT = featT + (size_t)which * BL * CIN;
  const int l0 = blockIdx.x * 32, c0 = blockIdx.y * 32;
  const int tx = threadIdx.x, ty = threadIdx.y;
  const float* p = in + ((size_t)b * CIN + c0 + ty) * L_ + l0 + tx;
#pragma unroll
  for (int i = 0; i < 32; i += 8) tile[ty + i][tx] = p[(size_t)i * L_];
  __syncthreads();
  unsigned short* q = outT + ((size_t)b * L_ + l0 + ty) * CIN + c0 + tx;
#pragma unroll
  for (int i = 0; i < 32; i += 8) q[(size_t)i * CIN] = f2bf(tile[tx][ty + i]);
}

// alpha: 4 lanes per token. hmid = gelu(hm0+hm1+ba1), logits = hmid@Wa2^T+ba2, softmax.
__global__ void k_alpha(const float* __restrict__ hm0, const float* __restrict__ hm1,
                        const float* __restrict__ ba1, const float* __restrict__ Wa2,
                        const float* __restrict__ ba2, float* __restrict__ alpha) {
  __shared__ float w2[K_ * DH];
  __shared__ float b1[DH];
  __shared__ float b2[K_];
  for (int i = threadIdx.x; i < K_ * DH; i += 256) w2[i] = Wa2[i];
  if (threadIdx.x < DH) b1[threadIdx.x] = ba1[threadIdx.x];
  if (threadIdx.x < K_) b2[threadIdx.x] = ba2[threadIdx.x];
  __syncthreads();
  const int token = blockIdx.x * 64 + (threadIdx.x >> 2);
  const int q = threadIdx.x & 3;            // 32-d slice owned by this lane
  float a0 = 0.f, a1 = 0.f, a2 = 0.f, a3 = 0.f;
  const size_t base = (size_t)token * DH + q * 32;
#pragma unroll
  for (int j4 = 0; j4 < 8; ++j4) {
    float4 h0 = *(const float4*)(hm0 + base + j4 * 4);
    float4 h1 = *(const float4*)(hm1 + base + j4 * 4);
    const float hv[4] = {h0.x + h1.x, h0.y + h1.y, h0.z + h1.z, h0.w + h1.w};
#pragma unroll
    for (int e = 0; e < 4; ++e) {
      const int d = q * 32 + j4 * 4 + e;
      float g = hv[e] + b1[d];
      g = 0.5f * g * (1.0f + erff(g * 0.70710678118654752f));
      a0 += g * w2[0 * DH + d];
      a1 += g * w2[1 * DH + d];
      a2 += g * w2[2 * DH + d];
      a3 += g * w2[3 * DH + d];
    }
  }
  a0 += __shfl_xor(a0, 1); a1 += __shfl_xor(a1, 1); a2 += __shfl_xor(a2, 1); a3 += __shfl_xor(a3, 1);
  a0 += __shfl_xor(a0, 2); a1 += __shfl_xor(a1, 2); a2 += __shfl_xor(a2, 2); a3 += __shfl_xor(a3, 2);
  a0 += b2[0]; a1 += b2[1]; a2 += b2[2]; a3 += b2[3];
  float m = fmaxf(fmaxf(a0, a1), fmaxf(a2, a3));
  float e0 = expf(a0 - m), e1 = expf(a1 - m), e2 = expf(a2 - m), e3 = expf(a3 - m);
  float inv = 1.f / (e0 + e1 + e2 + e3);
  float my = (q == 0) ? e0 : (q == 1) ? e1 : (q == 2) ? e2 : e3;
  alpha[(size_t)token * 4 + q] = my * inv;
}

// ---------------------------------------------------------------- scan (3-pass)
// a recomputed from alpha & A_base in-register; u read directly (f32).

__global__ void k_scanA(const float* __restrict__ u, const float* __restrict__ alpha,
                        const float* __restrict__ Abase,
                        float* __restrict__ P, float* __restrict__ Hend) {
  const int n = threadIdx.x;           // 512
  const int bc = blockIdx.x;           // B*NCHUNK = 512
  const int b = bc >> 7, c = bc & 127;
  const float A0 = Abase[n], A1 = Abase[N_ + n], A2 = Abase[2 * N_ + n], A3 = Abase[3 * N_ + n];
  const size_t tok0 = (size_t)b * L_ + (size_t)c * CLEN;
  float p = 1.f, h = 0.f;
  for (int l = 0; l < CLEN; ++l) {
    const size_t t = tok0 + l;
    float4 al = *(const float4*)(alpha + t * 4);
    float s = al.x * A0 + al.y * A1 + al.z * A2 + al.w * A3;
    float av = 1.f / (1.f + expf(-s));
    float uv = u[t * N_ + n];
    h = av * h + uv;
    p *= av;
  }
  P[(size_t)bc * N_ + n] = p;
  Hend[(size_t)bc * N_ + n] = h;
}

__global__ void k_scanB(const float* __restrict__ P, const float* __restrict__ Hend,
                        float* __restrict__ Hstart) {
  const int n = threadIdx.x;
  const int b = blockIdx.x;
  float h = 0.f;
  for (int c = 0; c < NCHUNK; ++c) {
    size_t idx = ((size_t)b * NCHUNK + c) * N_ + n;
    Hstart[idx] = h;
    h = P[idx] * h + Hend[idx];
  }
}

__global__ void k_scanC(const float* __restrict__ u, const float* __restrict__ alpha,
                        const float* __restrict__ Abase, const float* __restrict__ Hstart,
                        unsigned short* __restrict__ hbf) {
  const int n = threadIdx.x;
  const int bc = blockIdx.x;
  const int b = bc >> 7, c = bc & 127;
  const float A0 = Abase[n], A1 = Abase[N_ + n], A2 = Abase[2 * N_ + n], A3 = Abase[3 * N_ + n];
  const size_t tok0 = (size_t)b * L_ + (size_t)c * CLEN;
  float h = Hstart[(size_t)bc * N_ + n];
  for (int l = 0; l < CLEN; ++l) {
    const size_t t = tok0 + l;
    float4 al = *(const float4*)(alpha + t * 4);
    float s = al.x * A0 + al.y * A1 + al.z * A2 + al.w * A3;
    float av = 1.f / (1.f + expf(-s));
    float uv = u[t * N_ + n];
    h = av * h + uv;
    hbf[t * N_ + n] = f2bf(h);
  }
}

// ---------------------------------------------------------------- GEMM common
#define BM 128
#define BN 128
#define BK 32

#define GLL(src, dst)                                                                      \
  __builtin_amdgcn_global_load_lds((const __attribute__((address_space(1))) void*)(src),   \
                                   (__attribute__((address_space(3))) void*)(dst), 16, 0, 0)

// ---- engine 1: 256-thread 128x128, 2-phase dbuf w/ __syncthreads (small GEMMs)
template <int BIAS /*0,1 col,2 row*/, int EPI /*0 f32,1 bf16*/>
__global__ __launch_bounds__(256) void gemm_bt(
    const unsigned short* __restrict__ A, long sA,
    const unsigned short* __restrict__ Bm, long sB,
    const float* __restrict__ bias, long bS,
    void* __restrict__ Cv, long sC,
    int M, int N, int Kd, int lda, int ldb) {
  const int zb = blockIdx.z;
  A += (size_t)zb * sA;
  Bm += (size_t)zb * sB;
  if (BIAS) bias += (size_t)zb * bS;
  const int m0 = blockIdx.x * BM;
  const int n0 = blockIdx.y * BN;
  __shared__ __attribute__((aligned(16))) unsigned short As[2 * BM * BK];
  __shared__ __attribute__((aligned(16))) unsigned short Bs[2 * BN * BK];
  const int t = threadIdx.x;
  const int lane = t & 63;
  const int w = t >> 6;
  const int wm = (w >> 1) * 64;
  const int wn = (w & 1) * 64;

  f4 acc[4][4];
#pragma unroll
  for (int i = 0; i < 4; ++i)
#pragma unroll
    for (int j = 0; j < 4; ++j) acc[i][j] = (f4){0.f, 0.f, 0.f, 0.f};

  const int rS = t >> 2;
  const int cS = (t & 3) * 8;
  const unsigned short* gA = A + (size_t)(m0 + rS) * lda + cS;
  const unsigned short* gB = Bm + (size_t)(n0 + rS) * ldb + cS;
  const long rowStepA = (long)64 * lda;
  const long rowStepB = (long)64 * ldb;
  const int kg = (lane >> 4) * 8;
  const int r16 = lane & 15;

#define STAGE1(buf, kt)                                                 \
  do {                                                                  \
    const unsigned short* sA_ = gA + (size_t)(kt) * BK;                 \
    const unsigned short* sB_ = gB + (size_t)(kt) * BK;                 \
    unsigned short* dA_ = As + (buf) * (BM * BK) + t * 8;               \
    unsigned short* dB_ = Bs + (buf) * (BN * BK) + t * 8;               \
    GLL(sA_, dA_); GLL(sA_ + rowStepA, dA_ + 64 * BK);                  \
    GLL(sB_, dB_); GLL(sB_ + rowStepB, dB_ + 64 * BK);                  \
  } while (0)

  const int nIter = Kd / BK;
  STAGE1(0, 0);
  __syncthreads();
  int cur = 0;
  for (int kt = 0; kt < nIter; ++kt) {
    if (kt + 1 < nIter) STAGE1(cur ^ 1, kt + 1);
    const unsigned short* Ab = As + cur * (BM * BK);
    const unsigned short* Bb2 = Bs + cur * (BN * BK);
    bfrag af[4], bfr[4];
#pragma unroll
    for (int i = 0; i < 4; ++i) {
      af[i]  = *(const bfrag*)(Ab + (wm + i * 16 + r16) * BK + kg);
      bfr[i] = *(const bfrag*)(Bb2 + (wn + i * 16 + r16) * BK + kg);
    }
#pragma unroll
    for (int i = 0; i < 4; ++i)
#pragma unroll
      for (int j = 0; j < 4; ++j)
        acc[i][j] = __builtin_amdgcn_mfma_f32_16x16x32_bf16(af[i], bfr[j], acc[i][j], 0, 0, 0);
    __syncthreads();
    cur ^= 1;
  }
#undef STAGE1

  const int rowBase = m0 + wm + ((lane >> 4) << 2);
  const int colBase = n0 + wn + (lane & 15);
  float* Cf = (float*)Cv + (size_t)zb * sC;
  unsigned short* Cb = (unsigned short*)Cv + (size_t)zb * sC;
#pragma unroll
  for (int i = 0; i < 4; ++i) {
#pragma unroll
    for (int j = 0; j < 4; ++j) {
      const int col = colBase + j * 16;
#pragma unroll
      for (int r = 0; r < 4; ++r) {
        const int row = rowBase + i * 16 + r;
        float v = acc[i][j][r];
        if (BIAS == 1) v += bias[col];
        if (BIAS == 2) v += bias[row];
        if (EPI == 1) Cb[(size_t)row * N + col] = f2bf(v);
        else          Cf[(size_t)row * N + col] = v;
      }
    }
  }
}

// ---- engine 2: 512-thread 128x256, triple-buffered LDS, counted vmcnt + raw barrier
// (T3+T4: loads stay in flight across barriers — depth-2 prefetch)
// EPI: 0 f32 (+bias), 1 bf16 (+bias), 2 alpha-mix->f32 (ld=N/4), 3 alpha-mix->bf16
#define BM2 128
#define BN2 256

template <int BIAS, int EPI>
__global__ __launch_bounds__(512, 2) void gemm_bt2(
    const unsigned short* __restrict__ A, long sA,
    const unsigned short* __restrict__ Bm, long sB,
    const float* __restrict__ bias, long bS,
    const float* __restrict__ alphaP,
    void* __restrict__ Cv, long sC,
    int M, int N, int Kd, int lda, int ldb) {
  const int zb = blockIdx.z;
  A += (size_t)zb * sA;
  Bm += (size_t)zb * sB;
  if (BIAS) bias += (size_t)zb * bS;
  const int m0 = blockIdx.x * BM2;
  const int n0 = blockIdx.y * BN2;
  __shared__ __attribute__((aligned(16))) unsigned short As[3 * BM2 * BK]; // 24 KB
  __shared__ __attribute__((aligned(16))) unsigned short Bs[3 * BN2 * BK]; // 48 KB
  const int t = threadIdx.x;
  const int lane = t & 63;
  const int w = t >> 6;             // 0..7
  const int wm = (w >> 2) * 64;     // 2 rows of waves
  const int wn = (w & 3) * 64;      // 4 cols of waves

  f4 acc[4][4];
#pragma unroll
  for (int i = 0; i < 4; ++i)
#pragma unroll
    for (int j = 0; j < 4; ++j) acc[i][j] = (f4){0.f, 0.f, 0.f, 0.f};

  const int rS = t >> 2;            // 0..127
  const int cS = (t & 3) * 8;
  const unsigned short* gA = A + (size_t)(m0 + rS) * lda + cS;
  const unsigned short* gB = Bm + (size_t)(n0 + rS) * ldb + cS;
  const long rowStepB = (long)128 * ldb;
  const int kg = (lane >> 4) * 8;
  const int r16 = lane & 15;

#define STAGE2(slot, kt)                                                \
  do {                                                                  \
    const unsigned short* sA_ = gA + (size_t)(kt) * BK;                 \
    const unsigned short* sB_ = gB + (size_t)(kt) * BK;                 \
    unsigned short* dA_ = As + (slot) * (BM2 * BK) + t * 8;             \
    unsigned short* dB_ = Bs + (slot) * (BN2 * BK) + t * 8;             \
    GLL(sA_, dA_);                                                      \
    GLL(sB_, dB_);                                                      \
    GLL(sB_ + rowStepB, dB_ + BM2 * BK);                                \
  } while (0)

  const int nIter = Kd / BK;        // >= 8 for all uses
  STAGE2(0, 0);
  STAGE2(1, 1);
  int slot = 0;
  for (int kt = 0; kt < nIter; ++kt) {
    if (kt + 1 < nIter) asm volatile("s_waitcnt vmcnt(3)" ::: "memory");
    else                asm volatile("s_waitcnt vmcnt(0)" ::: "memory");
    __builtin_amdgcn_s_barrier();
    asm volatile("" ::: "memory");
    if (kt + 2 < nIter) {
      int s2 = slot + 2; if (s2 >= 3) s2 -= 3;
      STAGE2(s2, kt + 2);
    }
    const unsigned short* Ab = As + slot * (BM2 * BK);
    const unsigned short* Bb2 = Bs + slot * (BN2 * BK);
    bfrag af[4], bfr[4];
#pragma unroll
    for (int i = 0; i < 4; ++i) {
      af[i]  = *(const bfrag*)(Ab + (wm + i * 16 + r16) * BK + kg);
      bfr[i] = *(const bfrag*)(Bb2 + (wn + i * 16 + r16) * BK + kg);
    }
    __builtin_amdgcn_s_setprio(1);
#pragma unroll
    for (int i = 0; i < 4; ++i)
#pragma unroll
      for (int j = 0; j < 4; ++j)
        acc[i][j] = __builtin_amdgcn_mfma_f32_16x16x32_bf16(af[i], bfr[j], acc[i][j], 0, 0, 0);
    __builtin_amdgcn_s_setprio(0);
    asm volatile("" ::: "memory");
    slot = (slot == 2) ? 0 : slot + 1;
  }
#undef STAGE2

  const int rowBase = m0 + wm + ((lane >> 4) << 2);
  const int colBase = n0 + wn + (lane & 15);

  if (EPI >= 2) {
    const int kq = lane & 3;
    const int NO = N >> 2;
    float av[4][4];
#pragma unroll
    for (int i = 0; i < 4; ++i)
#pragma unroll
      for (int r = 0; r < 4; ++r)
        av[i][r] = alphaP[(size_t)(rowBase + i * 16 + r) * 4 + kq];
    float* Cf = (float*)Cv + (size_t)zb * sC;
    unsigned short* Cb = (unsigned short*)Cv + (size_t)zb * sC;
#pragma unroll
    for (int i = 0; i < 4; ++i)
#pragma unroll
      for (int j = 0; j < 4; ++j) {
        const int col = colBase + j * 16;
#pragma unroll
        for (int r = 0; r < 4; ++r) {
          float p = av[i][r] * acc[i][j][r];
          p += __shfl_xor(p, 1);
          p += __shfl_xor(p, 2);
          if (kq == 0) {
            const int row = rowBase + i * 16 + r;
            if (EPI == 2) Cf[(size_t)row * NO + (col >> 2)] = p;
            else          Cb[(size_t)row * NO + (col >> 2)] = f2bf(p);
          }
        }
      }
    return;
  }

  float* Cf = (float*)Cv + (size_t)zb * sC;
  unsigned short* Cb = (unsigned short*)Cv + (size_t)zb * sC;
#pragma unroll
  for (int i = 0; i < 4; ++i) {
#pragma unroll
    for (int j = 0; j < 4; ++j) {
      const int col = colBase + j * 16;
#pragma unroll
      for (int r = 0; r < 4; ++r) {
        const int row = rowBase + i * 16 + r;
        float v = acc[i][j][r];
        if (BIAS == 1) v += bias[col];
        if (BIAS == 2) v += bias[row];
        if (EPI == 1) Cb[(size_t)row * N + col] = f2bf(v);
        else          Cf[(size_t)row * N + col] = v;
      }
    }
  }
}

// ---------------------------------------------------------------- launch

extern "C" void kernel_launch(void* const* d_in, const int* in_sizes, int n_in,
                              void* d_out, int out_size, void* d_ws, size_t ws_size,
                              hipStream_t stream) {
  const float* feat  = (const float*)d_in[0];
  const float* hf    = (const float*)d_in[1];
  const float* Wf    = (const float*)d_in[2];
  const float* bfv   = (const float*)d_in[3];
  const float* Whf   = (const float*)d_in[4];
  const float* bhfv  = (const float*)d_in[5];
  const float* Wa1   = (const float*)d_in[6];
  const float* ba1   = (const float*)d_in[7];
  const float* Wa2   = (const float*)d_in[8];
  const float* ba2   = (const float*)d_in[9];
  const float* Abase = (const float*)d_in[10];
  const float* Bbase = (const float*)d_in[11];
  const float* Cbase = (const float*)d_in[12];
  const float* Wout  = (const float*)d_in[13];
  const float* bout  = (const float*)d_in[14];
  float* out = (float*)d_out;

  char* ws = (char*)d_ws;
  size_t off = 0;
  auto alloc = [&](size_t bytes) { void* p = ws + off; off += bytes; return p; };

  unsigned short* Wfb    = (unsigned short*)alloc((size_t)2 * D_ * CIN * 2); // Wfb+Whfb
  unsigned short* Wa1b   = (unsigned short*)alloc((size_t)DH * D_ * 2);
  unsigned short* Woutb  = (unsigned short*)alloc((size_t)CIN * D_ * 2);
  unsigned short* Bb16   = (unsigned short*)alloc((size_t)K_ * N_ * D_ * 2);
  unsigned short* Cb16   = (unsigned short*)alloc((size_t)K_ * D_ * N_ * 2);
  float*          biascat= (float*)alloc((size_t)2 * D_ * 4);
  float*          alpha  = (float*)alloc((size_t)BL * K_ * 4);
  float*          Pc     = (float*)alloc((size_t)B_ * NCHUNK * N_ * 4);
  float*          He     = (float*)alloc((size_t)B_ * NCHUNK * N_ * 4);
  float*          Hs     = (float*)alloc((size_t)B_ * NCHUNK * N_ * 4);
  unsigned short* hbf    = (unsigned short*)alloc((size_t)BL * N_ * 2);
  unsigned short* x      = (unsigned short*)alloc((size_t)BL * D_ * 2);
  unsigned short* thf    = (unsigned short*)alloc((size_t)BL * D_ * 2);
  unsigned short* featT  = (unsigned short*)alloc((size_t)BL * CIN * 2);
  unsigned short* hfT    = (unsigned short*)alloc((size_t)BL * CIN * 2);
  float*          u      = (float*)alloc((size_t)BL * N_ * 4);   // 33.5 MB

  // aliases (dead regions)
  float*          hm0 = (float*)featT;  // BL*DH f32 = 8.39 MB, after proj GEMM
  float*          hm1 = (float*)hfT;
  unsigned short* y   = thf;            // BL*D bf16, after hmid GEMM read thf

  if (ws_size < off) return;  // ~91 MB required

  // 1) weight conversions + base relayouts
  k_prep<<<dim3((3 * 65536 + 32768 + 2 * 524288 + 512 + 255) / 256), 256, 0, stream>>>(
      Wf, Whf, Wa1, Wout, Bbase, Cbase, bfv, bhfv, Wfb, Wa1b, Woutb, Bb16, Cb16, biascat);

  // 2) token-major transposed inputs (batched feat+hf)
  k_transpose2<<<dim3(L_ / 32, CIN / 32, 2 * B_), dim3(32, 8), 0, stream>>>(feat, hf, featT);

  // 3) projections batched z=2: x = featT@Wf^T+bf ; thf = hfT@Whf^T+bhf
  gemm_bt2<1, 1><<<dim3(BL / BM2, D_ / BN2, 2), 512, 0, stream>>>(
      featT, (long)BL * CIN, Wfb, (long)D_ * CIN, biascat, D_, nullptr,
      x, (long)BL * D_, BL, D_, CIN, CIN, CIN);

  // 4) hmid GEMM split-K z=2 (f32 slices; bias+GELU deferred to k_alpha)
  gemm_bt<0, 0><<<dim3(BL / BM, DH / BN, 2), 256, 0, stream>>>(
      thf, 128, Wa1b, 128, nullptr, 0,
      hm0, (long)BL * DH, BL, DH, 128, D_, D_);
  k_alpha<<<dim3(BL / 64), 256, 0, stream>>>(hm0, hm1, ba1, Wa2, ba2, alpha);

  // 5) u[t,n] = sum_k alpha_k (x @ B_base^T) : mix fused in epilogue (EPI=2)
  gemm_bt2<0, 2><<<dim3(BL / BM2, (K_ * N_) / BN2, 1), 512, 0, stream>>>(
      x, 0, Bb16, 0, nullptr, 0, alpha, u, 0, BL, K_ * N_, D_, D_, D_);

  // 6) chunked scan; a recomputed in-register; pass C writes h (bf16)
  k_scanA<<<dim3(B_ * NCHUNK), N_, 0, stream>>>(u, alpha, Abase, Pc, He);
  k_scanB<<<dim3(B_), N_, 0, stream>>>(Pc, He, Hs);
  k_scanC<<<dim3(B_ * NCHUNK), N_, 0, stream>>>(u, alpha, Abase, Hs, hbf);

  // 7) y[t,d] = sum_k alpha_k (h @ C_base^T) : mix fused in epilogue (EPI=3)
  gemm_bt2<0, 3><<<dim3(BL / BM2, (K_ * D_) / BN2, 1), 512, 0, stream>>>(
      hbf, 0, Cb16, 0, nullptr, 0, alpha, y, 0, BL, K_ * D_, N_, N_, N_);

  // 8) out[b,c,l] = Wout @ y_b^T + bout : batched z=4
  gemm_bt<2, 0><<<dim3(CIN / BM, L_ / BN, B_), 256, 0, stream>>>(
      Woutb, 0, y, (long)L_ * D_, bout, 0, out, (long)CIN * L_, CIN, L_, D_, D_, D_);
}

// Round 5
// 161.992 us; speedup vs baseline: 1.4998x; 1.0117x over previous
//
#include <hip/hip_runtime.h>
#include <hip/hip_bf16.h>
#include <math.h>

// Dims (fixed by the problem)
#define B_  4
#define CIN 256
#define L_  4096      // H*W = 64*64
#define D_  256
#define N_  512
#define K_  4
#define DH  128       // D/2
#define BL  (B_ * L_) // 16384 tokens

#define NCHUNK 128
#define CLEN   (L_ / NCHUNK) // 32

typedef __attribute__((ext_vector_type(8))) short bfrag;
typedef __attribute__((ext_vector_type(4))) float f4;

__device__ __forceinline__ float bf2f(unsigned short u) {
  return __uint_as_float(((unsigned int)u) << 16);
}
__device__ __forceinline__ unsigned short f2bf(float f) {
  unsigned int u = __float_as_uint(f);
  return (unsigned short)((u + 0x7FFFu + ((u >> 16) & 1u)) >> 16);
}

// ---------------------------------------------------------------- prep (all weight converts, 1 launch)
// Bb16 row (n*4+k) = B_base[k,n,:]   (K-contig over d)
// Cb16 row (d*4+k) = C_base[k,d,:]   (K-contig over n)
__global__ void k_prep(const float* __restrict__ Wf, const float* __restrict__ Whf,
                       const float* __restrict__ Wa1, const float* __restrict__ Wout,
                       const float* __restrict__ Bb, const float* __restrict__ Cb,
                       const float* __restrict__ bfv, const float* __restrict__ bhfv,
                       unsigned short* __restrict__ Wfb /*Wfb+Whfb adjacent*/,
                       unsigned short* __restrict__ Wa1b,
                       unsigned short* __restrict__ Woutb,
                       unsigned short* __restrict__ Bb16,
                       unsigned short* __restrict__ Cb16,
                       float* __restrict__ biascat) {
  int i = blockIdx.x * 256 + threadIdx.x;
  if (i < 65536) { Wfb[i] = f2bf(Wf[i]); return; } i -= 65536;
  if (i < 65536) { Wfb[65536 + i] = f2bf(Whf[i]); return; } i -= 65536;
  if (i < 32768) { Wa1b[i] = f2bf(Wa1[i]); return; } i -= 32768;
  if (i < 65536) { Woutb[i] = f2bf(Wout[i]); return; } i -= 65536;
  if (i < 524288) {  // B_base (K,N,D): i = (k<<17)|(n<<8)|d
    int d = i & 255, n = (i >> 8) & 511, k = i >> 17;
    Bb16[(((size_t)n << 2) | k) << 8 | d] = f2bf(Bb[i]);
    return;
  } i -= 524288;
  if (i < 524288) {  // C_base (K,D,N): i = (k<<17)|(d<<9)|nn
    int nn = i & 511, d = (i >> 9) & 255, k = i >> 17;
    Cb16[(((size_t)d << 2) | k) << 9 | nn] = f2bf(Cb[i]);
    return;
  } i -= 524288;
  if (i < 256) { biascat[i] = bfv[i]; return; } i -= 256;
  if (i < 256) { biascat[256 + i] = bhfv[i]; }
}

// feat/hf (B,C,L) f32 -> (B*L, C) bf16 ; z = which*4 + b
__global__ void k_transpose2(const float* __restrict__ feat, const float* __restrict__ hf,
                             unsigned short* __restrict__ featT /* hfT adjacent */) {
  __shared__ float tile[32][33];
  const int z = blockIdx.z;
  const int b = z & 3, which = z >> 2;
  const float* in = which ? hf : feat;
  unsigned short* outT = featT + (size_t)which * BL * CIN;
  const int l0 = blockIdx.x * 32, c0 = blockIdx.y * 32;
  const int tx = threadIdx.x, ty = threadIdx.y;
  const float* p = in + ((size_t)b * CIN + c0 + ty) * L_ + l0 + tx;
#pragma unroll
  for (int i = 0; i < 32; i += 8) tile[ty + i][tx] = p[(size_t)i * L_];
  __syncthreads();
  unsigned short* q = outT + ((size_t)b * L_ + l0 + ty) * CIN + c0 + tx;
#pragma unroll
  for (int i = 0; i < 32; i += 8) q[(size_t)i * CIN] = f2bf(tile[tx][ty + i]);
}

// alpha: 4 lanes per token. hmid = gelu(hm0+hm1+ba1), logits = hmid@Wa2^T+ba2, softmax.
__global__ void k_alpha(const float* __restrict__ hm0, const float* __restrict__ hm1,
                        const float* __restrict__ ba1, const float* __restrict__ Wa2,
                        const float* __restrict__ ba2, float* __restrict__ alpha) {
  __shared__ float w2[K_ * DH];
  __shared__ float b1[DH];
  __shared__ float b2[K_];
  for (int i = threadIdx.x; i < K_ * DH; i += 256) w2[i] = Wa2[i];
  if (threadIdx.x < DH) b1[threadIdx.x] = ba1[threadIdx.x];
  if (threadIdx.x < K_) b2[threadIdx.x] = ba2[threadIdx.x];
  __syncthreads();
  const int token = blockIdx.x * 64 + (threadIdx.x >> 2);
  const int q = threadIdx.x & 3;            // 32-d slice owned by this lane
  float a0 = 0.f, a1 = 0.f, a2 = 0.f, a3 = 0.f;
  const size_t base = (size_t)token * DH + q * 32;
#pragma unroll
  for (int j4 = 0; j4 < 8; ++j4) {
    float4 h0 = *(const float4*)(hm0 + base + j4 * 4);
    float4 h1 = *(const float4*)(hm1 + base + j4 * 4);
    const float hv[4] = {h0.x + h1.x, h0.y + h1.y, h0.z + h1.z, h0.w + h1.w};
#pragma unroll
    for (int e = 0; e < 4; ++e) {
      const int d = q * 32 + j4 * 4 + e;
      float g = hv[e] + b1[d];
      g = 0.5f * g * (1.0f + erff(g * 0.70710678118654752f));
      a0 += g * w2[0 * DH + d];
      a1 += g * w2[1 * DH + d];
      a2 += g * w2[2 * DH + d];
      a3 += g * w2[3 * DH + d];
    }
  }
  a0 += __shfl_xor(a0, 1); a1 += __shfl_xor(a1, 1); a2 += __shfl_xor(a2, 1); a3 += __shfl_xor(a3, 1);
  a0 += __shfl_xor(a0, 2); a1 += __shfl_xor(a1, 2); a2 += __shfl_xor(a2, 2); a3 += __shfl_xor(a3, 2);
  a0 += b2[0]; a1 += b2[1]; a2 += b2[2]; a3 += b2[3];
  float m = fmaxf(fmaxf(a0, a1), fmaxf(a2, a3));
  float e0 = expf(a0 - m), e1 = expf(a1 - m), e2 = expf(a2 - m), e3 = expf(a3 - m);
  float inv = 1.f / (e0 + e1 + e2 + e3);
  float my = (q == 0) ? e0 : (q == 1) ? e1 : (q == 2) ? e2 : e3;
  alpha[(size_t)token * 4 + q] = my * inv;
}

// ---------------------------------------------------------------- scan (3-pass)
// a recomputed from alpha & A_base in-register; u read as bf16.

__global__ void k_scanA(const unsigned short* __restrict__ u, const float* __restrict__ alpha,
                        const float* __restrict__ Abase,
                        float* __restrict__ P, float* __restrict__ Hend) {
  const int n = threadIdx.x;           // 512
  const int bc = blockIdx.x;           // B*NCHUNK = 512
  const int b = bc >> 7, c = bc & 127;
  const float A0 = Abase[n], A1 = Abase[N_ + n], A2 = Abase[2 * N_ + n], A3 = Abase[3 * N_ + n];
  const size_t tok0 = (size_t)b * L_ + (size_t)c * CLEN;
  float p = 1.f, h = 0.f;
  for (int l = 0; l < CLEN; ++l) {
    const size_t t = tok0 + l;
    float4 al = *(const float4*)(alpha + t * 4);
    float s = al.x * A0 + al.y * A1 + al.z * A2 + al.w * A3;
    float av = 1.f / (1.f + expf(-s));
    float uv = bf2f(u[t * N_ + n]);
    h = av * h + uv;
    p *= av;
  }
  P[(size_t)bc * N_ + n] = p;
  Hend[(size_t)bc * N_ + n] = h;
}

__global__ void k_scanB(const float* __restrict__ P, const float* __restrict__ Hend,
                        float* __restrict__ Hstart) {
  const int n = threadIdx.x;
  const int b = blockIdx.x;
  float h = 0.f;
  for (int c = 0; c < NCHUNK; ++c) {
    size_t idx = ((size_t)b * NCHUNK + c) * N_ + n;
    Hstart[idx] = h;
    h = P[idx] * h + Hend[idx];
  }
}

__global__ void k_scanC(const unsigned short* __restrict__ u, const float* __restrict__ alpha,
                        const float* __restrict__ Abase, const float* __restrict__ Hstart,
                        unsigned short* __restrict__ hbf) {
  const int n = threadIdx.x;
  const int bc = blockIdx.x;
  const int b = bc >> 7, c = bc & 127;
  const float A0 = Abase[n], A1 = Abase[N_ + n], A2 = Abase[2 * N_ + n], A3 = Abase[3 * N_ + n];
  const size_t tok0 = (size_t)b * L_ + (size_t)c * CLEN;
  float h = Hstart[(size_t)bc * N_ + n];
  for (int l = 0; l < CLEN; ++l) {
    const size_t t = tok0 + l;
    float4 al = *(const float4*)(alpha + t * 4);
    float s = al.x * A0 + al.y * A1 + al.z * A2 + al.w * A3;
    float av = 1.f / (1.f + expf(-s));
    float uv = bf2f(u[t * N_ + n]);
    h = av * h + uv;
    hbf[t * N_ + n] = f2bf(h);
  }
}

// ---------------------------------------------------------------- GEMM common
#define BM 128
#define BN 128
#define BK 32

#define GLL(src, dst)                                                                      \
  __builtin_amdgcn_global_load_lds((const __attribute__((address_space(1))) void*)(src),   \
                                   (__attribute__((address_space(3))) void*)(dst), 16, 0, 0)

// ---- engine 2: 512-thread 128x256, triple-buffered LDS, counted vmcnt + raw barrier
// (T3+T4: loads stay in flight across barriers — depth-2 prefetch)
// EPI: 0 f32 (+bias), 1 bf16 (+bias), 2 alpha-mix->f32 (ld=N/4), 3 alpha-mix->bf16
#define BM2 128
#define BN2 256

template <int BIAS, int EPI>
__global__ __launch_bounds__(512, 2) void gemm_bt2(
    const unsigned short* __restrict__ A, long sA,
    const unsigned short* __restrict__ Bm, long sB,
    const float* __restrict__ bias, long bS,
    const float* __restrict__ alphaP,
    void* __restrict__ Cv, long sC,
    int M, int N, int Kd, int lda, int ldb) {
  const int zb = blockIdx.z;
  A += (size_t)zb * sA;
  Bm += (size_t)zb * sB;
  if (BIAS) bias += (size_t)zb * bS;
  const int m0 = blockIdx.x * BM2;
  const int n0 = blockIdx.y * BN2;
  __shared__ __attribute__((aligned(16))) unsigned short As[3 * BM2 * BK]; // 24 KB
  __shared__ __attribute__((aligned(16))) unsigned short Bs[3 * BN2 * BK]; // 48 KB
  const int t = threadIdx.x;
  const int lane = t & 63;
  const int w = t >> 6;             // 0..7
  const int wm = (w >> 2) * 64;     // 2 rows of waves
  const int wn = (w & 3) * 64;      // 4 cols of waves

  f4 acc[4][4];
#pragma unroll
  for (int i = 0; i < 4; ++i)
#pragma unroll
    for (int j = 0; j < 4; ++j) acc[i][j] = (f4){0.f, 0.f, 0.f, 0.f};

  const int rS = t >> 2;            // 0..127
  const int cS = (t & 3) * 8;
  const unsigned short* gA = A + (size_t)(m0 + rS) * lda + cS;
  const unsigned short* gB = Bm + (size_t)(n0 + rS) * ldb + cS;
  const long rowStepB = (long)128 * ldb;
  const int kg = (lane >> 4) * 8;
  const int r16 = lane & 15;

#define STAGE2(slot, kt)                                                \
  do {                                                                  \
    const unsigned short* sA_ = gA + (size_t)(kt) * BK;                 \
    const unsigned short* sB_ = gB + (size_t)(kt) * BK;                 \
    unsigned short* dA_ = As + (slot) * (BM2 * BK) + t * 8;             \
    unsigned short* dB_ = Bs + (slot) * (BN2 * BK) + t * 8;             \
    GLL(sA_, dA_);                                                      \
    GLL(sB_, dB_);                                                      \
    GLL(sB_ + rowStepB, dB_ + BM2 * BK);                                \
  } while (0)

  const int nIter = Kd / BK;        // >= 8 for all uses
  STAGE2(0, 0);
  STAGE2(1, 1);
  int slot = 0;
  for (int kt = 0; kt < nIter; ++kt) {
    if (kt + 1 < nIter) asm volatile("s_waitcnt vmcnt(3)" ::: "memory");
    else                asm volatile("s_waitcnt vmcnt(0)" ::: "memory");
    __builtin_amdgcn_s_barrier();
    asm volatile("" ::: "memory");
    if (kt + 2 < nIter) {
      int s2 = slot + 2; if (s2 >= 3) s2 -= 3;
      STAGE2(s2, kt + 2);
    }
    const unsigned short* Ab = As + slot * (BM2 * BK);
    const unsigned short* Bb2 = Bs + slot * (BN2 * BK);
    bfrag af[4], bfr[4];
#pragma unroll
    for (int i = 0; i < 4; ++i) {
      af[i]  = *(const bfrag*)(Ab + (wm + i * 16 + r16) * BK + kg);
      bfr[i] = *(const bfrag*)(Bb2 + (wn + i * 16 + r16) * BK + kg);
    }
    __builtin_amdgcn_s_setprio(1);
#pragma unroll
    for (int i = 0; i < 4; ++i)
#pragma unroll
      for (int j = 0; j < 4; ++j)
        acc[i][j] = __builtin_amdgcn_mfma_f32_16x16x32_bf16(af[i], bfr[j], acc[i][j], 0, 0, 0);
    __builtin_amdgcn_s_setprio(0);
    asm volatile("" ::: "memory");
    slot = (slot == 2) ? 0 : slot + 1;
  }
#undef STAGE2

  const int rowBase = m0 + wm + ((lane >> 4) << 2);
  const int colBase = n0 + wn + (lane & 15);

  if (EPI >= 2) {
    const int kq = lane & 3;
    const int NO = N >> 2;
    float av[4][4];
#pragma unroll
    for (int i = 0; i < 4; ++i)
#pragma unroll
      for (int r = 0; r < 4; ++r)
        av[i][r] = alphaP[(size_t)(rowBase + i * 16 + r) * 4 + kq];
    float* Cf = (float*)Cv + (size_t)zb * sC;
    unsigned short* Cb = (unsigned short*)Cv + (size_t)zb * sC;
#pragma unroll
    for (int i = 0; i < 4; ++i)
#pragma unroll
      for (int j = 0; j < 4; ++j) {
        const int col = colBase + j * 16;
#pragma unroll
        for (int r = 0; r < 4; ++r) {
          float p = av[i][r] * acc[i][j][r];
          p += __shfl_xor(p, 1);
          p += __shfl_xor(p, 2);
          if (kq == 0) {
            const int row = rowBase + i * 16 + r;
            if (EPI == 2) Cf[(size_t)row * NO + (col >> 2)] = p;
            else          Cb[(size_t)row * NO + (col >> 2)] = f2bf(p);
          }
        }
      }
    return;
  }

  float* Cf = (float*)Cv + (size_t)zb * sC;
  unsigned short* Cb = (unsigned short*)Cv + (size_t)zb * sC;
#pragma unroll
  for (int i = 0; i < 4; ++i) {
#pragma unroll
    for (int j = 0; j < 4; ++j) {
      const int col = colBase + j * 16;
#pragma unroll
      for (int r = 0; r < 4; ++r) {
        const int row = rowBase + i * 16 + r;
        float v = acc[i][j][r];
        if (BIAS == 1) v += bias[col];
        if (BIAS == 2) v += bias[row];
        if (EPI == 1) Cb[(size_t)row * N + col] = f2bf(v);
        else          Cf[(size_t)row * N + col] = v;
      }
    }
  }
}

// ---- engine 3: 256-thread 128x128, triple-buffered LDS, counted vmcnt + raw barrier
// (same T3+T4 schedule as engine 2 at 4 waves; for small-N GEMMs needing >=256 blocks)
template <int BIAS, int EPI /*0 f32,1 bf16*/>
__global__ __launch_bounds__(256) void gemm_bt3(
    const unsigned short* __restrict__ A, long sA,
    const unsigned short* __restrict__ Bm, long sB,
    const float* __restrict__ bias, long bS,
    void* __restrict__ Cv, long sC,
    int M, int N, int Kd, int lda, int ldb) {
  const int zb = blockIdx.z;
  A += (size_t)zb * sA;
  Bm += (size_t)zb * sB;
  if (BIAS) bias += (size_t)zb * bS;
  const int m0 = blockIdx.x * BM;
  const int n0 = blockIdx.y * BN;
  __shared__ __attribute__((aligned(16))) unsigned short As[3 * BM * BK]; // 24 KB
  __shared__ __attribute__((aligned(16))) unsigned short Bs[3 * BN * BK]; // 24 KB
  const int t = threadIdx.x;
  const int lane = t & 63;
  const int w = t >> 6;
  const int wm = (w >> 1) * 64;
  const int wn = (w & 1) * 64;

  f4 acc[4][4];
#pragma unroll
  for (int i = 0; i < 4; ++i)
#pragma unroll
    for (int j = 0; j < 4; ++j) acc[i][j] = (f4){0.f, 0.f, 0.f, 0.f};

  const int rS = t >> 2;        // 0..63
  const int cS = (t & 3) * 8;
  const unsigned short* gA = A + (size_t)(m0 + rS) * lda + cS;
  const unsigned short* gB = Bm + (size_t)(n0 + rS) * ldb + cS;
  const long rowStepA = (long)64 * lda;
  const long rowStepB = (long)64 * ldb;
  const int kg = (lane >> 4) * 8;
  const int r16 = lane & 15;

#define STAGE3(slot, kt)                                                \
  do {                                                                  \
    const unsigned short* sA_ = gA + (size_t)(kt) * BK;                 \
    const unsigned short* sB_ = gB + (size_t)(kt) * BK;                 \
    unsigned short* dA_ = As + (slot) * (BM * BK) + t * 8;              \
    unsigned short* dB_ = Bs + (slot) * (BN * BK) + t * 8;              \
    GLL(sA_, dA_); GLL(sA_ + rowStepA, dA_ + 64 * BK);                  \
    GLL(sB_, dB_); GLL(sB_ + rowStepB, dB_ + 64 * BK);                  \
  } while (0)

  const int nIter = Kd / BK;    // >= 4 for all uses
  STAGE3(0, 0);
  STAGE3(1, 1);
  int slot = 0;
  for (int kt = 0; kt < nIter; ++kt) {
    if (kt + 1 < nIter) asm volatile("s_waitcnt vmcnt(4)" ::: "memory");
    else                asm volatile("s_waitcnt vmcnt(0)" ::: "memory");
    __builtin_amdgcn_s_barrier();
    asm volatile("" ::: "memory");
    if (kt + 2 < nIter) {
      int s2 = slot + 2; if (s2 >= 3) s2 -= 3;
      STAGE3(s2, kt + 2);
    }
    const unsigned short* Ab = As + slot * (BM * BK);
    const unsigned short* Bb2 = Bs + slot * (BN * BK);
    bfrag af[4], bfr[4];
#pragma unroll
    for (int i = 0; i < 4; ++i) {
      af[i]  = *(const bfrag*)(Ab + (wm + i * 16 + r16) * BK + kg);
      bfr[i] = *(const bfrag*)(Bb2 + (wn + i * 16 + r16) * BK + kg);
    }
    __builtin_amdgcn_s_setprio(1);
#pragma unroll
    for (int i = 0; i < 4; ++i)
#pragma unroll
      for (int j = 0; j < 4; ++j)
        acc[i][j] = __builtin_amdgcn_mfma_f32_16x16x32_bf16(af[i], bfr[j], acc[i][j], 0, 0, 0);
    __builtin_amdgcn_s_setprio(0);
    asm volatile("" ::: "memory");
    slot = (slot == 2) ? 0 : slot + 1;
  }
#undef STAGE3

  const int rowBase = m0 + wm + ((lane >> 4) << 2);
  const int colBase = n0 + wn + (lane & 15);
  float* Cf = (float*)Cv + (size_t)zb * sC;
  unsigned short* Cb = (unsigned short*)Cv + (size_t)zb * sC;
#pragma unroll
  for (int i = 0; i < 4; ++i) {
#pragma unroll
    for (int j = 0; j < 4; ++j) {
      const int col = colBase + j * 16;
#pragma unroll
      for (int r = 0; r < 4; ++r) {
        const int row = rowBase + i * 16 + r;
        float v = acc[i][j][r];
        if (BIAS == 1) v += bias[col];
        if (BIAS == 2) v += bias[row];
        if (EPI == 1) Cb[(size_t)row * N + col] = f2bf(v);
        else          Cf[(size_t)row * N + col] = v;
      }
    }
  }
}

// ---------------------------------------------------------------- launch

extern "C" void kernel_launch(void* const* d_in, const int* in_sizes, int n_in,
                              void* d_out, int out_size, void* d_ws, size_t ws_size,
                              hipStream_t stream) {
  const float* feat  = (const float*)d_in[0];
  const float* hf    = (const float*)d_in[1];
  const float* Wf    = (const float*)d_in[2];
  const float* bfv   = (const float*)d_in[3];
  const float* Whf   = (const float*)d_in[4];
  const float* bhfv  = (const float*)d_in[5];
  const float* Wa1   = (const float*)d_in[6];
  const float* ba1   = (const float*)d_in[7];
  const float* Wa2   = (const float*)d_in[8];
  const float* ba2   = (const float*)d_in[9];
  const float* Abase = (const float*)d_in[10];
  const float* Bbase = (const float*)d_in[11];
  const float* Cbase = (const float*)d_in[12];
  const float* Wout  = (const float*)d_in[13];
  const float* bout  = (const float*)d_in[14];
  float* out = (float*)d_out;

  char* ws = (char*)d_ws;
  size_t off = 0;
  auto alloc = [&](size_t bytes) { void* p = ws + off; off += bytes; return p; };

  unsigned short* Wfb    = (unsigned short*)alloc((size_t)2 * D_ * CIN * 2); // Wfb+Whfb
  unsigned short* Wa1b   = (unsigned short*)alloc((size_t)DH * D_ * 2);
  unsigned short* Woutb  = (unsigned short*)alloc((size_t)CIN * D_ * 2);
  unsigned short* Bb16   = (unsigned short*)alloc((size_t)K_ * N_ * D_ * 2);
  unsigned short* Cb16   = (unsigned short*)alloc((size_t)K_ * D_ * N_ * 2);
  float*          biascat= (float*)alloc((size_t)2 * D_ * 4);
  float*          alpha  = (float*)alloc((size_t)BL * K_ * 4);
  float*          Pc     = (float*)alloc((size_t)B_ * NCHUNK * N_ * 4);
  float*          He     = (float*)alloc((size_t)B_ * NCHUNK * N_ * 4);
  float*          Hs     = (float*)alloc((size_t)B_ * NCHUNK * N_ * 4);
  unsigned short* hbf    = (unsigned short*)alloc((size_t)BL * N_ * 2);
  unsigned short* x      = (unsigned short*)alloc((size_t)BL * D_ * 2);
  unsigned short* thf    = (unsigned short*)alloc((size_t)BL * D_ * 2);
  unsigned short* featT  = (unsigned short*)alloc((size_t)BL * CIN * 2);
  unsigned short* hfT    = (unsigned short*)alloc((size_t)BL * CIN * 2);
  unsigned short* u16    = (unsigned short*)alloc((size_t)BL * N_ * 2);   // 16.8 MB

  // aliases (dead regions)
  float*          hm0 = (float*)featT;  // BL*DH f32 = 8.39 MB, after proj GEMM
  float*          hm1 = (float*)hfT;
  unsigned short* y   = thf;            // BL*D bf16, after hmid GEMM read thf

  if (ws_size < off) return;  // ~74 MB required

  // 1) weight conversions + base relayouts
  k_prep<<<dim3((3 * 65536 + 32768 + 2 * 524288 + 512 + 255) / 256), 256, 0, stream>>>(
      Wf, Whf, Wa1, Wout, Bbase, Cbase, bfv, bhfv, Wfb, Wa1b, Woutb, Bb16, Cb16, biascat);

  // 2) token-major transposed inputs (batched feat+hf)
  k_transpose2<<<dim3(L_ / 32, CIN / 32, 2 * B_), dim3(32, 8), 0, stream>>>(feat, hf, featT);

  // 3) projections batched z=2: x = featT@Wf^T+bf ; thf = hfT@Whf^T+bhf
  gemm_bt2<1, 1><<<dim3(BL / BM2, D_ / BN2, 2), 512, 0, stream>>>(
      featT, (long)BL * CIN, Wfb, (long)D_ * CIN, biascat, D_, nullptr,
      x, (long)BL * D_, BL, D_, CIN, CIN, CIN);

  // 4) hmid GEMM split-K z=2 (f32 slices; bias+GELU deferred to k_alpha)
  gemm_bt3<0, 0><<<dim3(BL / BM, DH / BN, 2), 256, 0, stream>>>(
      thf, 128, Wa1b, 128, nullptr, 0,
      hm0, (long)BL * DH, BL, DH, 128, D_, D_);
  k_alpha<<<dim3(BL / 64), 256, 0, stream>>>(hm0, hm1, ba1, Wa2, ba2, alpha);

  // 5) u[t,n] = sum_k alpha_k (x @ B_base^T) : mix fused in epilogue, bf16 (EPI=3)
  gemm_bt2<0, 3><<<dim3(BL / BM2, (K_ * N_) / BN2, 1), 512, 0, stream>>>(
      x, 0, Bb16, 0, nullptr, 0, alpha, u16, 0, BL, K_ * N_, D_, D_, D_);

  // 6) chunked scan; a recomputed in-register; pass C writes h (bf16)
  k_scanA<<<dim3(B_ * NCHUNK), N_, 0, stream>>>(u16, alpha, Abase, Pc, He);
  k_scanB<<<dim3(B_), N_, 0, stream>>>(Pc, He, Hs);
  k_scanC<<<dim3(B_ * NCHUNK), N_, 0, stream>>>(u16, alpha, Abase, Hs, hbf);

  // 7) y[t,d] = sum_k alpha_k (h @ C_base^T) : mix fused in epilogue (EPI=3)
  gemm_bt2<0, 3><<<dim3(BL / BM2, (K_ * D_) / BN2, 1), 512, 0, stream>>>(
      hbf, 0, Cb16, 0, nullptr, 0, alpha, y, 0, BL, K_ * D_, N_, N_, N_);

  // 8) out[b,c,l] = Wout @ y_b^T + bout : batched z=4 (engine 3)
  gemm_bt3<2, 0><<<dim3(CIN / BM, L_ / BN, B_), 256, 0, stream>>>(
      Woutb, 0, y, (long)L_ * D_, bout, 0, out, (long)CIN * L_, CIN, L_, D_, D_, D_);
}

// Round 6
// 160.376 us; speedup vs baseline: 1.5149x; 1.0101x over previous
//
#include <hip/hip_runtime.h>
#include <hip/hip_bf16.h>
#include <math.h>

// Dims (fixed by the problem)
#define B_  4
#define CIN 256
#define L_  4096      // H*W = 64*64
#define D_  256
#define N_  512
#define K_  4
#define DH  128       // D/2
#define BL  (B_ * L_) // 16384 tokens

#define NCHUNK 128
#define CLEN   (L_ / NCHUNK) // 32

typedef __attribute__((ext_vector_type(8))) short bfrag;
typedef __attribute__((ext_vector_type(4))) float f4;

__device__ __forceinline__ float bf2f(unsigned short u) {
  return __uint_as_float(((unsigned int)u) << 16);
}
__device__ __forceinline__ unsigned short f2bf(float f) {
  unsigned int u = __float_as_uint(f);
  return (unsigned short)((u + 0x7FFFu + ((u >> 16) & 1u)) >> 16);
}

// ---------------------------------------------------------------- prep (all weight converts, 1 launch)
// Bb16 row (n*4+k) = B_base[k,n,:]   (K-contig over d)
// Cb16 row (d*4+k) = C_base[k,d,:]   (K-contig over n)
__global__ void k_prep(const float* __restrict__ Wf, const float* __restrict__ Whf,
                       const float* __restrict__ Wa1, const float* __restrict__ Wout,
                       const float* __restrict__ Bb, const float* __restrict__ Cb,
                       const float* __restrict__ bfv, const float* __restrict__ bhfv,
                       unsigned short* __restrict__ Wfb /*Wfb+Whfb adjacent*/,
                       unsigned short* __restrict__ Wa1b,
                       unsigned short* __restrict__ Woutb,
                       unsigned short* __restrict__ Bb16,
                       unsigned short* __restrict__ Cb16,
                       float* __restrict__ biascat) {
  int i = blockIdx.x * 256 + threadIdx.x;
  if (i < 65536) { Wfb[i] = f2bf(Wf[i]); return; } i -= 65536;
  if (i < 65536) { Wfb[65536 + i] = f2bf(Whf[i]); return; } i -= 65536;
  if (i < 32768) { Wa1b[i] = f2bf(Wa1[i]); return; } i -= 32768;
  if (i < 65536) { Woutb[i] = f2bf(Wout[i]); return; } i -= 65536;
  if (i < 524288) {  // B_base (K,N,D): i = (k<<17)|(n<<8)|d
    int d = i & 255, n = (i >> 8) & 511, k = i >> 17;
    Bb16[(((size_t)n << 2) | k) << 8 | d] = f2bf(Bb[i]);
    return;
  } i -= 524288;
  if (i < 524288) {  // C_base (K,D,N): i = (k<<17)|(d<<9)|nn
    int nn = i & 511, d = (i >> 9) & 255, k = i >> 17;
    Cb16[(((size_t)d << 2) | k) << 9 | nn] = f2bf(Cb[i]);
    return;
  } i -= 524288;
  if (i < 256) { biascat[i] = bfv[i]; return; } i -= 256;
  if (i < 256) { biascat[256 + i] = bhfv[i]; }
}

// feat/hf (B,C,L) f32 -> (B*L, C) bf16 ; z = which*4 + b
__global__ void k_transpose2(const float* __restrict__ feat, const float* __restrict__ hf,
                             unsigned short* __restrict__ featT /* hfT adjacent */) {
  __shared__ float tile[32][33];
  const int z = blockIdx.z;
  const int b = z & 3, which = z >> 2;
  const float* in = which ? hf : feat;
  unsigned short* outT = featT + (size_t)which * BL * CIN;
  const int l0 = blockIdx.x * 32, c0 = blockIdx.y * 32;
  const int tx = threadIdx.x, ty = threadIdx.y;
  const float* p = in + ((size_t)b * CIN + c0 + ty) * L_ + l0 + tx;
#pragma unroll
  for (int i = 0; i < 32; i += 8) tile[ty + i][tx] = p[(size_t)i * L_];
  __syncthreads();
  unsigned short* q = outT + ((size_t)b * L_ + l0 + ty) * CIN + c0 + tx;
#pragma unroll
  for (int i = 0; i < 32; i += 8) q[(size_t)i * CIN] = f2bf(tile[tx][ty + i]);
}

// alpha: 4 lanes per token. hmid = gelu(hm0+hm1+ba1), logits = hmid@Wa2^T+ba2, softmax.
__global__ void k_alpha(const float* __restrict__ hm0, const float* __restrict__ hm1,
                        const float* __restrict__ ba1, const float* __restrict__ Wa2,
                        const float* __restrict__ ba2, float* __restrict__ alpha) {
  __shared__ float w2[K_ * DH];
  __shared__ float b1[DH];
  __shared__ float b2[K_];
  for (int i = threadIdx.x; i < K_ * DH; i += 256) w2[i] = Wa2[i];
  if (threadIdx.x < DH) b1[threadIdx.x] = ba1[threadIdx.x];
  if (threadIdx.x < K_) b2[threadIdx.x] = ba2[threadIdx.x];
  __syncthreads();
  const int token = blockIdx.x * 64 + (threadIdx.x >> 2);
  const int q = threadIdx.x & 3;            // 32-d slice owned by this lane
  float a0 = 0.f, a1 = 0.f, a2 = 0.f, a3 = 0.f;
  const size_t base = (size_t)token * DH + q * 32;
#pragma unroll
  for (int j4 = 0; j4 < 8; ++j4) {
    float4 h0 = *(const float4*)(hm0 + base + j4 * 4);
    float4 h1 = *(const float4*)(hm1 + base + j4 * 4);
    const float hv[4] = {h0.x + h1.x, h0.y + h1.y, h0.z + h1.z, h0.w + h1.w};
#pragma unroll
    for (int e = 0; e < 4; ++e) {
      const int d = q * 32 + j4 * 4 + e;
      float g = hv[e] + b1[d];
      g = 0.5f * g * (1.0f + erff(g * 0.70710678118654752f));
      a0 += g * w2[0 * DH + d];
      a1 += g * w2[1 * DH + d];
      a2 += g * w2[2 * DH + d];
      a3 += g * w2[3 * DH + d];
    }
  }
  a0 += __shfl_xor(a0, 1); a1 += __shfl_xor(a1, 1); a2 += __shfl_xor(a2, 1); a3 += __shfl_xor(a3, 1);
  a0 += __shfl_xor(a0, 2); a1 += __shfl_xor(a1, 2); a2 += __shfl_xor(a2, 2); a3 += __shfl_xor(a3, 2);
  a0 += b2[0]; a1 += b2[1]; a2 += b2[2]; a3 += b2[3];
  float m = fmaxf(fmaxf(a0, a1), fmaxf(a2, a3));
  float e0 = expf(a0 - m), e1 = expf(a1 - m), e2 = expf(a2 - m), e3 = expf(a3 - m);
  float inv = 1.f / (e0 + e1 + e2 + e3);
  float my = (q == 0) ? e0 : (q == 1) ? e1 : (q == 2) ? e2 : e3;
  alpha[(size_t)token * 4 + q] = my * inv;
}

// ---------------------------------------------------------------- scan (3-pass)
// a recomputed from alpha & A_base in-register; u read as bf16.

__global__ void k_scanA(const unsigned short* __restrict__ u, const float* __restrict__ alpha,
                        const float* __restrict__ Abase,
                        float* __restrict__ P, float* __restrict__ Hend) {
  const int n = threadIdx.x;           // 512
  const int bc = blockIdx.x;           // B*NCHUNK = 512
  const int b = bc >> 7, c = bc & 127;
  const float A0 = Abase[n], A1 = Abase[N_ + n], A2 = Abase[2 * N_ + n], A3 = Abase[3 * N_ + n];
  const size_t tok0 = (size_t)b * L_ + (size_t)c * CLEN;
  float p = 1.f, h = 0.f;
  for (int l = 0; l < CLEN; ++l) {
    const size_t t = tok0 + l;
    float4 al = *(const float4*)(alpha + t * 4);
    float s = al.x * A0 + al.y * A1 + al.z * A2 + al.w * A3;
    float av = 1.f / (1.f + expf(-s));
    float uv = bf2f(u[t * N_ + n]);
    h = av * h + uv;
    p *= av;
  }
  P[(size_t)bc * N_ + n] = p;
  Hend[(size_t)bc * N_ + n] = h;
}

__global__ void k_scanB(const float* __restrict__ P, const float* __restrict__ Hend,
                        float* __restrict__ Hstart) {
  const int n = threadIdx.x;
  const int b = blockIdx.x;
  float h = 0.f;
  for (int c = 0; c < NCHUNK; ++c) {
    size_t idx = ((size_t)b * NCHUNK + c) * N_ + n;
    Hstart[idx] = h;
    h = P[idx] * h + Hend[idx];
  }
}

__global__ void k_scanC(const unsigned short* __restrict__ u, const float* __restrict__ alpha,
                        const float* __restrict__ Abase, const float* __restrict__ Hstart,
                        unsigned short* __restrict__ hbf) {
  const int n = threadIdx.x;
  const int bc = blockIdx.x;
  const int b = bc >> 7, c = bc & 127;
  const float A0 = Abase[n], A1 = Abase[N_ + n], A2 = Abase[2 * N_ + n], A3 = Abase[3 * N_ + n];
  const size_t tok0 = (size_t)b * L_ + (size_t)c * CLEN;
  float h = Hstart[(size_t)bc * N_ + n];
  for (int l = 0; l < CLEN; ++l) {
    const size_t t = tok0 + l;
    float4 al = *(const float4*)(alpha + t * 4);
    float s = al.x * A0 + al.y * A1 + al.z * A2 + al.w * A3;
    float av = 1.f / (1.f + expf(-s));
    float uv = bf2f(u[t * N_ + n]);
    h = av * h + uv;
    hbf[t * N_ + n] = f2bf(h);
  }
}

// ---------------------------------------------------------------- GEMM common
// LDS XOR swizzle (T2, rule #21 both-sides): 64-B rows, slot(16B) ^= (row>>1)&3.
// Staged linearly by global_load_lds (thread t -> row t>>2, slot t&3), so the
// GLOBAL source column is pre-swizzled: col_slot = (t&3) ^ ((t>>3)&3).
// Read side: fragment slot = (lane>>4) ^ ((r16>>1)&3)  (wave-uniform across i/j
// because wm, wn, i*16 are all ≡ 0 mod 8). Rows 0-7 cover all 8 bank-quads,
// rows 8-15 alias 2-way (free, m136).
#define BM 128
#define BN 128
#define BK 32

#define GLL(src, dst)                                                                      \
  __builtin_amdgcn_global_load_lds((const __attribute__((address_space(1))) void*)(src),   \
                                   (__attribute__((address_space(3))) void*)(dst), 16, 0, 0)

// ---- engine 2: 512-thread 128x256, triple-buffered LDS, counted vmcnt + raw barrier
// EPI: 0 f32 (+bias), 1 bf16 (+bias), 2 alpha-mix->f32 (ld=N/4), 3 alpha-mix->bf16
#define BM2 128
#define BN2 256

template <int BIAS, int EPI>
__global__ __launch_bounds__(512, 2) void gemm_bt2(
    const unsigned short* __restrict__ A, long sA,
    const unsigned short* __restrict__ Bm, long sB,
    const float* __restrict__ bias, long bS,
    const float* __restrict__ alphaP,
    void* __restrict__ Cv, long sC,
    int M, int N, int Kd, int lda, int ldb) {
  const int zb = blockIdx.z;
  A += (size_t)zb * sA;
  Bm += (size_t)zb * sB;
  if (BIAS) bias += (size_t)zb * bS;
  const int m0 = blockIdx.x * BM2;
  const int n0 = blockIdx.y * BN2;
  __shared__ __attribute__((aligned(16))) unsigned short As[3 * BM2 * BK]; // 24 KB
  __shared__ __attribute__((aligned(16))) unsigned short Bs[3 * BN2 * BK]; // 48 KB
  const int t = threadIdx.x;
  const int lane = t & 63;
  const int w = t >> 6;             // 0..7
  const int wm = (w >> 2) * 64;     // 2 rows of waves
  const int wn = (w & 3) * 64;      // 4 cols of waves

  f4 acc[4][4];
#pragma unroll
  for (int i = 0; i < 4; ++i)
#pragma unroll
    for (int j = 0; j < 4; ++j) acc[i][j] = (f4){0.f, 0.f, 0.f, 0.f};

  const int rS = t >> 2;            // 0..127
  const int cS = (((t & 3) ^ ((t >> 3) & 3))) * 8;   // pre-swizzled source slot
  const unsigned short* gA = A + (size_t)(m0 + rS) * lda + cS;
  const unsigned short* gB = Bm + (size_t)(n0 + rS) * ldb + cS;
  const long rowStepB = (long)128 * ldb;
  const int r16 = lane & 15;
  const int sx = (r16 >> 1) & 3;                     // read-side swizzle
  const int kg = (((lane >> 4) ^ sx)) * 8;           // swizzled fragment slot

#define STAGE2(slot, kt)                                                \
  do {                                                                  \
    const unsigned short* sA_ = gA + (size_t)(kt) * BK;                 \
    const unsigned short* sB_ = gB + (size_t)(kt) * BK;                 \
    unsigned short* dA_ = As + (slot) * (BM2 * BK) + t * 8;             \
    unsigned short* dB_ = Bs + (slot) * (BN2 * BK) + t * 8;             \
    GLL(sA_, dA_);                                                      \
    GLL(sB_, dB_);                                                      \
    GLL(sB_ + rowStepB, dB_ + BM2 * BK);                                \
  } while (0)

  const int nIter = Kd / BK;        // >= 8 for all uses
  STAGE2(0, 0);
  STAGE2(1, 1);
  int slot = 0;
  for (int kt = 0; kt < nIter; ++kt) {
    if (kt + 1 < nIter) asm volatile("s_waitcnt vmcnt(3)" ::: "memory");
    else                asm volatile("s_waitcnt vmcnt(0)" ::: "memory");
    __builtin_amdgcn_s_barrier();
    asm volatile("" ::: "memory");
    if (kt + 2 < nIter) {
      int s2 = slot + 2; if (s2 >= 3) s2 -= 3;
      STAGE2(s2, kt + 2);
    }
    const unsigned short* Ab = As + slot * (BM2 * BK);
    const unsigned short* Bb2 = Bs + slot * (BN2 * BK);
    bfrag af[4], bfr[4];
#pragma unroll
    for (int i = 0; i < 4; ++i) {
      af[i]  = *(const bfrag*)(Ab + (wm + i * 16 + r16) * BK + kg);
      bfr[i] = *(const bfrag*)(Bb2 + (wn + i * 16 + r16) * BK + kg);
    }
    __builtin_amdgcn_s_setprio(1);
#pragma unroll
    for (int i = 0; i < 4; ++i)
#pragma unroll
      for (int j = 0; j < 4; ++j)
        acc[i][j] = __builtin_amdgcn_mfma_f32_16x16x32_bf16(af[i], bfr[j], acc[i][j], 0, 0, 0);
    __builtin_amdgcn_s_setprio(0);
    asm volatile("" ::: "memory");
    slot = (slot == 2) ? 0 : slot + 1;
  }
#undef STAGE2

  const int rowBase = m0 + wm + ((lane >> 4) << 2);
  const int colBase = n0 + wn + (lane & 15);

  if (EPI >= 2) {
    const int kq = lane & 3;
    const int NO = N >> 2;
    float av[4][4];
#pragma unroll
    for (int i = 0; i < 4; ++i)
#pragma unroll
      for (int r = 0; r < 4; ++r)
        av[i][r] = alphaP[(size_t)(rowBase + i * 16 + r) * 4 + kq];
    float* Cf = (float*)Cv + (size_t)zb * sC;
    unsigned short* Cb = (unsigned short*)Cv + (size_t)zb * sC;
#pragma unroll
    for (int i = 0; i < 4; ++i)
#pragma unroll
      for (int j = 0; j < 4; ++j) {
        const int col = colBase + j * 16;
#pragma unroll
        for (int r = 0; r < 4; ++r) {
          float p = av[i][r] * acc[i][j][r];
          p += __shfl_xor(p, 1);
          p += __shfl_xor(p, 2);
          if (kq == 0) {
            const int row = rowBase + i * 16 + r;
            if (EPI == 2) Cf[(size_t)row * NO + (col >> 2)] = p;
            else          Cb[(size_t)row * NO + (col >> 2)] = f2bf(p);
          }
        }
      }
    return;
  }

  float* Cf = (float*)Cv + (size_t)zb * sC;
  unsigned short* Cb = (unsigned short*)Cv + (size_t)zb * sC;
#pragma unroll
  for (int i = 0; i < 4; ++i) {
#pragma unroll
    for (int j = 0; j < 4; ++j) {
      const int col = colBase + j * 16;
#pragma unroll
      for (int r = 0; r < 4; ++r) {
        const int row = rowBase + i * 16 + r;
        float v = acc[i][j][r];
        if (BIAS == 1) v += bias[col];
        if (BIAS == 2) v += bias[row];
        if (EPI == 1) Cb[(size_t)row * N + col] = f2bf(v);
        else          Cf[(size_t)row * N + col] = v;
      }
    }
  }
}

// ---- engine 3: 256-thread 128x128, triple-buffered LDS, counted vmcnt + raw barrier
template <int BIAS, int EPI /*0 f32,1 bf16*/>
__global__ __launch_bounds__(256) void gemm_bt3(
    const unsigned short* __restrict__ A, long sA,
    const unsigned short* __restrict__ Bm, long sB,
    const float* __restrict__ bias, long bS,
    void* __restrict__ Cv, long sC,
    int M, int N, int Kd, int lda, int ldb) {
  const int zb = blockIdx.z;
  A += (size_t)zb * sA;
  Bm += (size_t)zb * sB;
  if (BIAS) bias += (size_t)zb * bS;
  const int m0 = blockIdx.x * BM;
  const int n0 = blockIdx.y * BN;
  __shared__ __attribute__((aligned(16))) unsigned short As[3 * BM * BK]; // 24 KB
  __shared__ __attribute__((aligned(16))) unsigned short Bs[3 * BN * BK]; // 24 KB
  const int t = threadIdx.x;
  const int lane = t & 63;
  const int w = t >> 6;
  const int wm = (w >> 1) * 64;
  const int wn = (w & 1) * 64;

  f4 acc[4][4];
#pragma unroll
  for (int i = 0; i < 4; ++i)
#pragma unroll
    for (int j = 0; j < 4; ++j) acc[i][j] = (f4){0.f, 0.f, 0.f, 0.f};

  const int rS = t >> 2;        // 0..63
  const int cS = (((t & 3) ^ ((t >> 3) & 3))) * 8;   // pre-swizzled source slot
  const unsigned short* gA = A + (size_t)(m0 + rS) * lda + cS;
  const unsigned short* gB = Bm + (size_t)(n0 + rS) * ldb + cS;
  const long rowStepA = (long)64 * lda;
  const long rowStepB = (long)64 * ldb;
  const int r16 = lane & 15;
  const int sx = (r16 >> 1) & 3;
  const int kg = (((lane >> 4) ^ sx)) * 8;

#define STAGE3(slot, kt)                                                \
  do {                                                                  \
    const unsigned short* sA_ = gA + (size_t)(kt) * BK;                 \
    const unsigned short* sB_ = gB + (size_t)(kt) * BK;                 \
    unsigned short* dA_ = As + (slot) * (BM * BK) + t * 8;              \
    unsigned short* dB_ = Bs + (slot) * (BN * BK) + t * 8;              \
    GLL(sA_, dA_); GLL(sA_ + rowStepA, dA_ + 64 * BK);                  \
    GLL(sB_, dB_); GLL(sB_ + rowStepB, dB_ + 64 * BK);                  \
  } while (0)

  const int nIter = Kd / BK;    // >= 4 for all uses
  STAGE3(0, 0);
  STAGE3(1, 1);
  int slot = 0;
  for (int kt = 0; kt < nIter; ++kt) {
    if (kt + 1 < nIter) asm volatile("s_waitcnt vmcnt(4)" ::: "memory");
    else                asm volatile("s_waitcnt vmcnt(0)" ::: "memory");
    __builtin_amdgcn_s_barrier();
    asm volatile("" ::: "memory");
    if (kt + 2 < nIter) {
      int s2 = slot + 2; if (s2 >= 3) s2 -= 3;
      STAGE3(s2, kt + 2);
    }
    const unsigned short* Ab = As + slot * (BM * BK);
    const unsigned short* Bb2 = Bs + slot * (BN * BK);
    bfrag af[4], bfr[4];
#pragma unroll
    for (int i = 0; i < 4; ++i) {
      af[i]  = *(const bfrag*)(Ab + (wm + i * 16 + r16) * BK + kg);
      bfr[i] = *(const bfrag*)(Bb2 + (wn + i * 16 + r16) * BK + kg);
    }
    __builtin_amdgcn_s_setprio(1);
#pragma unroll
    for (int i = 0; i < 4; ++i)
#pragma unroll
      for (int j = 0; j < 4; ++j)
        acc[i][j] = __builtin_amdgcn_mfma_f32_16x16x32_bf16(af[i], bfr[j], acc[i][j], 0, 0, 0);
    __builtin_amdgcn_s_setprio(0);
    asm volatile("" ::: "memory");
    slot = (slot == 2) ? 0 : slot + 1;
  }
#undef STAGE3

  const int rowBase = m0 + wm + ((lane >> 4) << 2);
  const int colBase = n0 + wn + (lane & 15);
  float* Cf = (float*)Cv + (size_t)zb * sC;
  unsigned short* Cb = (unsigned short*)Cv + (size_t)zb * sC;
#pragma unroll
  for (int i = 0; i < 4; ++i) {
#pragma unroll
    for (int j = 0; j < 4; ++j) {
      const int col = colBase + j * 16;
#pragma unroll
      for (int r = 0; r < 4; ++r) {
        const int row = rowBase + i * 16 + r;
        float v = acc[i][j][r];
        if (BIAS == 1) v += bias[col];
        if (BIAS == 2) v += bias[row];
        if (EPI == 1) Cb[(size_t)row * N + col] = f2bf(v);
        else          Cf[(size_t)row * N + col] = v;
      }
    }
  }
}

// ---------------------------------------------------------------- launch

extern "C" void kernel_launch(void* const* d_in, const int* in_sizes, int n_in,
                              void* d_out, int out_size, void* d_ws, size_t ws_size,
                              hipStream_t stream) {
  const float* feat  = (const float*)d_in[0];
  const float* hf    = (const float*)d_in[1];
  const float* Wf    = (const float*)d_in[2];
  const float* bfv   = (const float*)d_in[3];
  const float* Whf   = (const float*)d_in[4];
  const float* bhfv  = (const float*)d_in[5];
  const float* Wa1   = (const float*)d_in[6];
  const float* ba1   = (const float*)d_in[7];
  const float* Wa2   = (const float*)d_in[8];
  const float* ba2   = (const float*)d_in[9];
  const float* Abase = (const float*)d_in[10];
  const float* Bbase = (const float*)d_in[11];
  const float* Cbase = (const float*)d_in[12];
  const float* Wout  = (const float*)d_in[13];
  const float* bout  = (const float*)d_in[14];
  float* out = (float*)d_out;

  char* ws = (char*)d_ws;
  size_t off = 0;
  auto alloc = [&](size_t bytes) { void* p = ws + off; off += bytes; return p; };

  unsigned short* Wfb    = (unsigned short*)alloc((size_t)2 * D_ * CIN * 2); // Wfb+Whfb
  unsigned short* Wa1b   = (unsigned short*)alloc((size_t)DH * D_ * 2);
  unsigned short* Woutb  = (unsigned short*)alloc((size_t)CIN * D_ * 2);
  unsigned short* Bb16   = (unsigned short*)alloc((size_t)K_ * N_ * D_ * 2);
  unsigned short* Cb16   = (unsigned short*)alloc((size_t)K_ * D_ * N_ * 2);
  float*          biascat= (float*)alloc((size_t)2 * D_ * 4);
  float*          alpha  = (float*)alloc((size_t)BL * K_ * 4);
  float*          Pc     = (float*)alloc((size_t)B_ * NCHUNK * N_ * 4);
  float*          He     = (float*)alloc((size_t)B_ * NCHUNK * N_ * 4);
  float*          Hs     = (float*)alloc((size_t)B_ * NCHUNK * N_ * 4);
  unsigned short* hbf    = (unsigned short*)alloc((size_t)BL * N_ * 2);
  unsigned short* x      = (unsigned short*)alloc((size_t)BL * D_ * 2);
  unsigned short* thf    = (unsigned short*)alloc((size_t)BL * D_ * 2);
  unsigned short* featT  = (unsigned short*)alloc((size_t)BL * CIN * 2);
  unsigned short* hfT    = (unsigned short*)alloc((size_t)BL * CIN * 2);
  unsigned short* u16    = (unsigned short*)alloc((size_t)BL * N_ * 2);   // 16.8 MB

  // aliases (dead regions)
  float*          hm0 = (float*)featT;  // BL*DH f32 = 8.39 MB, after proj GEMM
  float*          hm1 = (float*)hfT;
  unsigned short* y   = thf;            // BL*D bf16, after hmid GEMM read thf

  if (ws_size < off) return;  // ~74 MB required

  // 1) weight conversions + base relayouts
  k_prep<<<dim3((3 * 65536 + 32768 + 2 * 524288 + 512 + 255) / 256), 256, 0, stream>>>(
      Wf, Whf, Wa1, Wout, Bbase, Cbase, bfv, bhfv, Wfb, Wa1b, Woutb, Bb16, Cb16, biascat);

  // 2) token-major transposed inputs (batched feat+hf)
  k_transpose2<<<dim3(L_ / 32, CIN / 32, 2 * B_), dim3(32, 8), 0, stream>>>(feat, hf, featT);

  // 3) projections batched z=2: x = featT@Wf^T+bf ; thf = hfT@Whf^T+bhf
  gemm_bt2<1, 1><<<dim3(BL / BM2, D_ / BN2, 2), 512, 0, stream>>>(
      featT, (long)BL * CIN, Wfb, (long)D_ * CIN, biascat, D_, nullptr,
      x, (long)BL * D_, BL, D_, CIN, CIN, CIN);

  // 4) hmid GEMM split-K z=2 (f32 slices; bias+GELU deferred to k_alpha)
  gemm_bt3<0, 0><<<dim3(BL / BM, DH / BN, 2), 256, 0, stream>>>(
      thf, 128, Wa1b, 128, nullptr, 0,
      hm0, (long)BL * DH, BL, DH, 128, D_, D_);
  k_alpha<<<dim3(BL / 64), 256, 0, stream>>>(hm0, hm1, ba1, Wa2, ba2, alpha);

  // 5) u[t,n] = sum_k alpha_k (x @ B_base^T) : mix fused in epilogue, bf16 (EPI=3)
  gemm_bt2<0, 3><<<dim3(BL / BM2, (K_ * N_) / BN2, 1), 512, 0, stream>>>(
      x, 0, Bb16, 0, nullptr, 0, alpha, u16, 0, BL, K_ * N_, D_, D_, D_);

  // 6) chunked scan; a recomputed in-register; pass C writes h (bf16)
  k_scanA<<<dim3(B_ * NCHUNK), N_, 0, stream>>>(u16, alpha, Abase, Pc, He);
  k_scanB<<<dim3(B_), N_, 0, stream>>>(Pc, He, Hs);
  k_scanC<<<dim3(B_ * NCHUNK), N_, 0, stream>>>(u16, alpha, Abase, Hs, hbf);

  // 7) y[t,d] = sum_k alpha_k (h @ C_base^T) : mix fused in epilogue (EPI=3)
  gemm_bt2<0, 3><<<dim3(BL / BM2, (K_ * D_) / BN2, 1), 512, 0, stream>>>(
      hbf, 0, Cb16, 0, nullptr, 0, alpha, y, 0, BL, K_ * D_, N_, N_, N_);

  // 8) out[b,c,l] = Wout @ y_b^T + bout : batched z=4 (engine 3)
  gemm_bt3<2, 0><<<dim3(CIN / BM, L_ / BN, B_), 256, 0, stream>>>(
      Woutb, 0, y, (long)L_ * D_, bout, 0, out, (long)CIN * L_, CIN, L_, D_, D_, D_);
}